// Round 1
// baseline (892.872 us; speedup 1.0000x reference)
//
#include <hip/hip_runtime.h>
#include <hip/hip_bf16.h>

// ARMA GNN (K=3 stacks, T=2 layers, F_in=64, DIM=32) on MI355X.
// Strategy: device-built CSR (dst-grouped) -> gather-based propagation
// (no float atomics), features stored node-major [N][K*32] for coalesced
// 3x128B gathers per edge, act/root/bias fused into prop epilogue.

#define KSTACK 3
#define DIM    32
#define FDIM   96   // KSTACK*DIM

// ---------------- CSR build ----------------

__global__ void zero_int_kernel(int* __restrict__ p, int n) {
    int i = blockIdx.x * 256 + threadIdx.x;
    if (i < n) p[i] = 0;
}

__global__ void count_deg_kernel(const int* __restrict__ dst, int* __restrict__ deg, int E) {
    int i = blockIdx.x * 256 + threadIdx.x;
    if (i < E) atomicAdd(&deg[dst[i]], 1);
}

__global__ void dinv_kernel(const int* __restrict__ deg, float* __restrict__ dinv, int N) {
    int i = blockIdx.x * 256 + threadIdx.x;
    if (i < N) {
        int d = deg[i];
        dinv[i] = (d > 0) ? rsqrtf((float)d) : 0.0f;
    }
}

__global__ __launch_bounds__(512) void scan1_kernel(const int* __restrict__ deg,
                                                    int* __restrict__ offsets,
                                                    int* __restrict__ bsums, int N) {
    __shared__ int tmp[512];
    int t = threadIdx.x;
    int i = blockIdx.x * 512 + t;
    int v = (i < N) ? deg[i] : 0;
    tmp[t] = v;
    __syncthreads();
    for (int off = 1; off < 512; off <<= 1) {
        int add = (t >= off) ? tmp[t - off] : 0;
        __syncthreads();
        tmp[t] += add;
        __syncthreads();
    }
    if (i < N) offsets[i] = tmp[t] - v;          // block-local exclusive
    if (t == 511) bsums[blockIdx.x] = tmp[511];  // block total
}

__global__ void scan2_kernel(int* __restrict__ bsums, int nb) {
    if (blockIdx.x == 0 && threadIdx.x == 0) {
        int run = 0;
        for (int b = 0; b < nb; ++b) { int v = bsums[b]; bsums[b] = run; run += v; }
    }
}

__global__ void scan3_kernel(int* __restrict__ offsets, int* __restrict__ cursor,
                             const int* __restrict__ bsums, int N, int E) {
    int i = blockIdx.x * 256 + threadIdx.x;
    if (i < N) {
        int v = offsets[i] + bsums[i >> 9];
        offsets[i] = v;
        cursor[i]  = v;
    }
    if (i == 0) offsets[N] = E;
}

__global__ void fill_csr_kernel(const int* __restrict__ src, const int* __restrict__ dst,
                                const float* __restrict__ dinv, int* __restrict__ cursor,
                                int* __restrict__ csr_src, float* __restrict__ csr_w, int E) {
    int e = blockIdx.x * 256 + threadIdx.x;
    if (e < E) {
        int s = src[e], d = dst[e];
        int pos = atomicAdd(&cursor[d], 1);
        csr_src[pos] = s;
        csr_w[pos]   = dinv[s] * dinv[d];
    }
}

// ---------------- dense GEMMs ----------------

// out[n][k*32+o]  = sum_f x[n][f] * wA[k][f][o]
// root[n][k*32+o] = sum_f x[n][f] * wB[k][f][o]
template <int FIN>
__global__ __launch_bounds__(256) void mm_init_kernel(
    const float* __restrict__ x,   // [N, FIN]
    const float* __restrict__ wA,  // [K, FIN, 32]
    const float* __restrict__ wB,  // [K, FIN, 32]
    float* __restrict__ outA,      // [N, 96]
    float* __restrict__ outB,      // [N, 96]
    int N)
{
    __shared__ float swA[KSTACK * FIN * 32];
    __shared__ float swB[KSTACK * FIN * 32];
    __shared__ float sx[8 * FIN];
    const int tid = threadIdx.x;
    for (int i = tid; i < KSTACK * FIN * 32; i += 256) { swA[i] = wA[i]; swB[i] = wB[i]; }
    const int n0 = blockIdx.x * 8;
    for (int i = tid; i < 8 * FIN; i += 256) {
        int j = i / FIN, f = i % FIN;
        int n = n0 + j; if (n >= N) n = N - 1;
        sx[i] = x[(long)n * FIN + f];
    }
    __syncthreads();
    const int o = tid & 31;
    const int j = tid >> 5;
    const long n = n0 + j;
    if (n >= N) return;
    float accA[KSTACK] = {0.f, 0.f, 0.f};
    float accB[KSTACK] = {0.f, 0.f, 0.f};
    const float* xr = sx + j * FIN;
    #pragma unroll
    for (int f = 0; f < FIN; ++f) {
        float xv = xr[f];
        #pragma unroll
        for (int k = 0; k < KSTACK; ++k) {
            accA[k] += xv * swA[(k * FIN + f) * 32 + o];
            accB[k] += xv * swB[(k * FIN + f) * 32 + o];
        }
    }
    #pragma unroll
    for (int k = 0; k < KSTACK; ++k) {
        outA[n * FDIM + k * 32 + o] = accA[k];
        outB[n * FDIM + k * 32 + o] = accB[k];
    }
}

// out[n][k*32+o] = sum_f in[n][k*32+f] * w[k][f][o]
__global__ __launch_bounds__(256) void mm_mid_kernel(
    const float* __restrict__ in,  // [N, 96]
    const float* __restrict__ w,   // [K, 32, 32]
    float* __restrict__ out, int N)
{
    __shared__ float sw[KSTACK * 32 * 32];
    __shared__ float sx[8 * FDIM];
    const int tid = threadIdx.x;
    for (int i = tid; i < KSTACK * 32 * 32; i += 256) sw[i] = w[i];
    const long n0 = (long)blockIdx.x * 8;
    for (int i = tid; i < 8 * FDIM; i += 256) {
        long n = n0 + i / FDIM; if (n >= N) n = N - 1;
        sx[i] = in[n * FDIM + (i % FDIM)];
    }
    __syncthreads();
    const int o = tid & 31;
    const int j = tid >> 5;
    const long n = n0 + j;
    if (n >= N) return;
    #pragma unroll
    for (int k = 0; k < KSTACK; ++k) {
        float acc = 0.f;
        #pragma unroll
        for (int f = 0; f < 32; ++f)
            acc += sx[j * FDIM + k * 32 + f] * sw[(k * 32 + f) * 32 + o];
        out[n * FDIM + k * 32 + o] = acc;
    }
}

// ---------------- propagation (gather, fused epilogue) ----------------

template <bool RELU>
__global__ __launch_bounds__(256) void prop_act_kernel(
    const float* __restrict__ in,       // [N, 96]
    const int*   __restrict__ offsets,  // [N+1]
    const int*   __restrict__ csr_src,  // [E]
    const float* __restrict__ csr_w,    // [E]
    const float* __restrict__ root,     // [N, 96]
    const float* __restrict__ bias,     // [K*32]
    float* __restrict__ out, int N)
{
    const int lane = threadIdx.x & 31;
    const int j    = threadIdx.x >> 5;
    const long d   = (long)blockIdx.x * 8 + j;
    if (d >= N) return;
    const int s0 = offsets[d], s1 = offsets[d + 1];
    float a0 = 0.f, a1 = 0.f, a2 = 0.f;
    for (int i = s0; i < s1; ++i) {
        const int   s = csr_src[i];
        const float w = csr_w[i];
        const float* p = in + (long)s * FDIM;
        a0 += w * p[lane];
        a1 += w * p[32 + lane];
        a2 += w * p[64 + lane];
    }
    float v0 = a0 + root[d * FDIM + lane]      + bias[lane];
    float v1 = a1 + root[d * FDIM + 32 + lane] + bias[32 + lane];
    float v2 = a2 + root[d * FDIM + 64 + lane] + bias[64 + lane];
    if (RELU) { v0 = fmaxf(v0, 0.f); v1 = fmaxf(v1, 0.f); v2 = fmaxf(v2, 0.f); }
    out[d * FDIM + lane]      = v0;
    out[d * FDIM + 32 + lane] = v1;
    out[d * FDIM + 64 + lane] = v2;
}

// ---------------- mean over stacks ----------------

template <bool RELU>
__global__ void mean_kernel(const float* __restrict__ in, float* __restrict__ out, int N) {
    int i = blockIdx.x * 256 + threadIdx.x;  // over N*32
    if (i < N * 32) {
        int n = i >> 5, f = i & 31;
        float v = (in[(long)n * FDIM + f] + in[(long)n * FDIM + 32 + f] + in[(long)n * FDIM + 64 + f]) * (1.0f / 3.0f);
        if (RELU) v = fmaxf(v, 0.f);
        out[i] = v;
    }
}

// ---------------- launch ----------------

extern "C" void kernel_launch(void* const* d_in, const int* in_sizes, int n_in,
                              void* d_out, int out_size, void* d_ws, size_t ws_size,
                              hipStream_t stream) {
    const float* x       = (const float*)d_in[0];
    const int*   edge    = (const int*)  d_in[1];
    const float* w1_init = (const float*)d_in[2];
    const float* w1      = (const float*)d_in[3];
    const float* w1_root = (const float*)d_in[4];
    const float* b1      = (const float*)d_in[5];
    const float* w2_init = (const float*)d_in[6];
    const float* w2      = (const float*)d_in[7];
    const float* w2_root = (const float*)d_in[8];
    const float* b2      = (const float*)d_in[9];
    float* out = (float*)d_out;

    const int N = in_sizes[0] / 64;
    const int E = in_sizes[1] / 2;
    const int* src = edge;
    const int* dst = edge + E;

    // workspace carve (256B aligned)
    char* p = (char*)d_ws;
    auto alloc = [&](size_t bytes) { void* r = (void*)p; p += (bytes + 255) & ~(size_t)255; return r; };
    int*   deg      = (int*)  alloc((size_t)N * 4);
    float* dinv     = (float*)alloc((size_t)N * 4);
    int*   offsets  = (int*)  alloc((size_t)(N + 1) * 4);
    int*   cursor   = (int*)  alloc((size_t)N * 4);
    const int nScanBlocks = (N + 511) / 512;
    int*   bsums    = (int*)  alloc((size_t)nScanBlocks * 4);
    int*   csr_src  = (int*)  alloc((size_t)E * 4);
    float* csr_w    = (float*)alloc((size_t)E * 4);
    float* bufA     = (float*)alloc((size_t)N * FDIM * 4);
    float* bufB     = (float*)alloc((size_t)N * FDIM * 4);
    float* rootb    = (float*)alloc((size_t)N * FDIM * 4);
    float* hbuf     = (float*)alloc((size_t)N * DIM * 4);
    (void)ws_size; (void)n_in; (void)out_size;

    const int gN   = (N + 255) / 256;
    const int gE   = (E + 255) / 256;
    const int gNod = (N + 7) / 8;        // 8 nodes per 256-thread block
    const int gNF  = (N * 32 + 255) / 256;

    // ---- graph structure (rebuilt every call; deterministic topology) ----
    zero_int_kernel<<<gN, 256, 0, stream>>>(deg, N);
    count_deg_kernel<<<gE, 256, 0, stream>>>(dst, deg, E);
    dinv_kernel<<<gN, 256, 0, stream>>>(deg, dinv, N);
    scan1_kernel<<<nScanBlocks, 512, 0, stream>>>(deg, offsets, bsums, N);
    scan2_kernel<<<1, 64, 0, stream>>>(bsums, nScanBlocks);
    scan3_kernel<<<gN, 256, 0, stream>>>(offsets, cursor, bsums, N, E);
    fill_csr_kernel<<<gE, 256, 0, stream>>>(src, dst, dinv, cursor, csr_src, csr_w, E);

    // ---- layer 1 (act = relu) ----
    mm_init_kernel<64><<<gNod, 256, 0, stream>>>(x, w1_init, w1_root, bufA, rootb, N);
    prop_act_kernel<true><<<gNod, 256, 0, stream>>>(bufA, offsets, csr_src, csr_w, rootb, b1, bufB, N);
    mm_mid_kernel<<<gNod, 256, 0, stream>>>(bufB, w1, bufA, N);
    prop_act_kernel<true><<<gNod, 256, 0, stream>>>(bufA, offsets, csr_src, csr_w, rootb, b1, bufB, N);
    mean_kernel<true><<<gNF, 256, 0, stream>>>(bufB, hbuf, N);   // h = relu(mean_k)

    // ---- layer 2 (act = identity) ----
    mm_init_kernel<32><<<gNod, 256, 0, stream>>>(hbuf, w2_init, w2_root, bufA, rootb, N);
    prop_act_kernel<false><<<gNod, 256, 0, stream>>>(bufA, offsets, csr_src, csr_w, rootb, b2, bufB, N);
    mm_mid_kernel<<<gNod, 256, 0, stream>>>(bufB, w2, bufA, N);
    prop_act_kernel<false><<<gNod, 256, 0, stream>>>(bufA, offsets, csr_src, csr_w, rootb, b2, bufB, N);
    mean_kernel<false><<<gNF, 256, 0, stream>>>(bufB, out, N);
}

// Round 2
// 815.984 us; speedup vs baseline: 1.0942x; 1.0942x over previous
//
#include <hip/hip_runtime.h>
#include <hip/hip_bf16.h>

// ARMA GNN (K=3 stacks, T=2 layers, F_in=64, DIM=32) on MI355X.
// Round 2: dinv folded into feature rows (no csr_w), bf16 gather tables,
// mm_mid fused into prop1 epilogue, mean fused into prop2 epilogue.

#define KSTACK 3
#define DIM    32
#define FDIM   96   // KSTACK*DIM

typedef __hip_bfloat16 bf16;

// ---------------- CSR build ----------------

__global__ void zero_int_kernel(int* __restrict__ p, int n) {
    int i = blockIdx.x * 256 + threadIdx.x;
    if (i < n) p[i] = 0;
}

__global__ void count_deg_kernel(const int* __restrict__ dst, int* __restrict__ deg, int E) {
    int i = blockIdx.x * 256 + threadIdx.x;
    if (i < E) atomicAdd(&deg[dst[i]], 1);
}

__global__ void dinv_kernel(const int* __restrict__ deg, float* __restrict__ dinv, int N) {
    int i = blockIdx.x * 256 + threadIdx.x;
    if (i < N) {
        int d = deg[i];
        dinv[i] = (d > 0) ? rsqrtf((float)d) : 0.0f;
    }
}

__global__ __launch_bounds__(512) void scan1_kernel(const int* __restrict__ deg,
                                                    int* __restrict__ offsets,
                                                    int* __restrict__ bsums, int N) {
    __shared__ int tmp[512];
    int t = threadIdx.x;
    int i = blockIdx.x * 512 + t;
    int v = (i < N) ? deg[i] : 0;
    tmp[t] = v;
    __syncthreads();
    for (int off = 1; off < 512; off <<= 1) {
        int add = (t >= off) ? tmp[t - off] : 0;
        __syncthreads();
        tmp[t] += add;
        __syncthreads();
    }
    if (i < N) offsets[i] = tmp[t] - v;          // block-local exclusive
    if (t == 511) bsums[blockIdx.x] = tmp[511];  // block total
}

__global__ void scan2_kernel(int* __restrict__ bsums, int nb) {
    if (blockIdx.x == 0 && threadIdx.x == 0) {
        int run = 0;
        for (int b = 0; b < nb; ++b) { int v = bsums[b]; bsums[b] = run; run += v; }
    }
}

__global__ void scan3_kernel(int* __restrict__ offsets, int* __restrict__ cursor,
                             const int* __restrict__ bsums, int N, int E) {
    int i = blockIdx.x * 256 + threadIdx.x;
    if (i < N) {
        int v = offsets[i] + bsums[i >> 9];
        offsets[i] = v;
        cursor[i]  = v;
    }
    if (i == 0) offsets[N] = E;
}

__global__ void fill_csr_kernel(const int* __restrict__ src, const int* __restrict__ dst,
                                int* __restrict__ cursor, int* __restrict__ csr_src, int E) {
    int e = blockIdx.x * 256 + threadIdx.x;
    if (e < E) {
        int s = src[e], d = dst[e];
        int pos = atomicAdd(&cursor[d], 1);
        csr_src[pos] = s;
    }
}

// ---------------- init GEMM ----------------
// outA[n][k*32+o] = dinv[n] * sum_f x[n][f]*wA[k][f][o]   (bf16, pre-scaled gather row)
// outB[n][k*32+o] = sum_f x[n][f]*wB[k][f][o]             (fp32 root term)
template <int FIN>
__global__ __launch_bounds__(256) void mm_init_kernel(
    const float* __restrict__ x,    // [N, FIN]
    const float* __restrict__ wA,   // [K, FIN, 32]
    const float* __restrict__ wB,   // [K, FIN, 32]
    const float* __restrict__ dinv, // [N]
    bf16*  __restrict__ outA,       // [N, 96]
    float* __restrict__ outB,       // [N, 96]
    int N)
{
    __shared__ float swA[KSTACK * FIN * 32];
    __shared__ float swB[KSTACK * FIN * 32];
    __shared__ float sx[8 * FIN];
    const int tid = threadIdx.x;
    for (int i = tid; i < KSTACK * FIN * 32; i += 256) { swA[i] = wA[i]; swB[i] = wB[i]; }
    const int n0 = blockIdx.x * 8;
    for (int i = tid; i < 8 * FIN; i += 256) {
        int j = i / FIN, f = i % FIN;
        int n = n0 + j; if (n >= N) n = N - 1;
        sx[i] = x[(long)n * FIN + f];
    }
    __syncthreads();
    const int o = tid & 31;
    const int j = tid >> 5;
    const long n = n0 + j;
    if (n >= N) return;
    float accA[KSTACK] = {0.f, 0.f, 0.f};
    float accB[KSTACK] = {0.f, 0.f, 0.f};
    const float* xr = sx + j * FIN;
    #pragma unroll
    for (int f = 0; f < FIN; ++f) {
        float xv = xr[f];
        #pragma unroll
        for (int k = 0; k < KSTACK; ++k) {
            accA[k] += xv * swA[(k * FIN + f) * 32 + o];
            accB[k] += xv * swB[(k * FIN + f) * 32 + o];
        }
    }
    const float di = dinv[n];
    #pragma unroll
    for (int k = 0; k < KSTACK; ++k) {
        outA[n * FDIM + k * 32 + o] = __float2bfloat16(accA[k] * di);
        outB[n * FDIM + k * 32 + o] = accB[k];
    }
}

// ---------------- prop #1: gather + act + fused 32x32 GEMV, bf16-scaled out ----
// v[k] = act(dinv[d]*sum_{s in nbrs} in[s][k] + root[d][k] + bias[k])
// out[d][k][o] = bf16( dinv[d] * sum_f v[k][f]*w[k][f][o] )
template <bool RELU>
__global__ __launch_bounds__(256) void prop_mm_kernel(
    const bf16*  __restrict__ in,       // [N, 96] pre-scaled by dinv[src]
    const int*   __restrict__ offsets,  // [N+1]
    const int*   __restrict__ csr_src,  // [E]
    const float* __restrict__ dinv,     // [N]
    const float* __restrict__ root,     // [N, 96]
    const float* __restrict__ bias,     // [96]
    const float* __restrict__ w,        // [K,32,32]
    bf16* __restrict__ out, int N)
{
    __shared__ float sw[KSTACK * 32 * 32];
    __shared__ float sv[8][FDIM];
    const int tid = threadIdx.x;
    for (int i = tid; i < KSTACK * 32 * 32; i += 256) sw[i] = w[i];
    __syncthreads();
    const int lane = tid & 31;
    const int j    = tid >> 5;
    const long d   = (long)blockIdx.x * 8 + j;
    if (d >= N) return;
    const int s0 = offsets[d], s1 = offsets[d + 1];
    float a0 = 0.f, a1 = 0.f, a2 = 0.f;
    for (int i = s0; i < s1; ++i) {
        const bf16* p = in + (long)csr_src[i] * FDIM;
        a0 += __bfloat162float(p[lane]);
        a1 += __bfloat162float(p[32 + lane]);
        a2 += __bfloat162float(p[64 + lane]);
    }
    const float di = dinv[d];
    float v0 = a0 * di + root[d * FDIM + lane]      + bias[lane];
    float v1 = a1 * di + root[d * FDIM + 32 + lane] + bias[32 + lane];
    float v2 = a2 * di + root[d * FDIM + 64 + lane] + bias[64 + lane];
    if (RELU) { v0 = fmaxf(v0, 0.f); v1 = fmaxf(v1, 0.f); v2 = fmaxf(v2, 0.f); }
    // per-half-wave LDS transpose: same wave writes then reads its own row -> no barrier
    sv[j][lane]      = v0;
    sv[j][32 + lane] = v1;
    sv[j][64 + lane] = v2;
    float o0 = 0.f, o1 = 0.f, o2 = 0.f;
    #pragma unroll
    for (int f = 0; f < 32; ++f) {
        o0 += sv[j][f]      * sw[(0 * 32 + f) * 32 + lane];
        o1 += sv[j][32 + f] * sw[(1 * 32 + f) * 32 + lane];
        o2 += sv[j][64 + f] * sw[(2 * 32 + f) * 32 + lane];
    }
    out[d * FDIM + lane]      = __float2bfloat16(o0 * di);
    out[d * FDIM + 32 + lane] = __float2bfloat16(o1 * di);
    out[d * FDIM + 64 + lane] = __float2bfloat16(o2 * di);
}

// ---------------- prop #2: gather + act + mean over stacks (fp32 out) -------
template <bool RELU, bool OUTER_RELU>
__global__ __launch_bounds__(256) void prop_mean_kernel(
    const bf16*  __restrict__ in,       // [N, 96] pre-scaled by dinv[src]
    const int*   __restrict__ offsets,
    const int*   __restrict__ csr_src,
    const float* __restrict__ dinv,
    const float* __restrict__ root,     // [N, 96]
    const float* __restrict__ bias,     // [96]
    float* __restrict__ out,            // [N, 32]
    int N)
{
    const int lane = threadIdx.x & 31;
    const int j    = threadIdx.x >> 5;
    const long d   = (long)blockIdx.x * 8 + j;
    if (d >= N) return;
    const int s0 = offsets[d], s1 = offsets[d + 1];
    float a0 = 0.f, a1 = 0.f, a2 = 0.f;
    for (int i = s0; i < s1; ++i) {
        const bf16* p = in + (long)csr_src[i] * FDIM;
        a0 += __bfloat162float(p[lane]);
        a1 += __bfloat162float(p[32 + lane]);
        a2 += __bfloat162float(p[64 + lane]);
    }
    const float di = dinv[d];
    float v0 = a0 * di + root[d * FDIM + lane]      + bias[lane];
    float v1 = a1 * di + root[d * FDIM + 32 + lane] + bias[32 + lane];
    float v2 = a2 * di + root[d * FDIM + 64 + lane] + bias[64 + lane];
    if (RELU) { v0 = fmaxf(v0, 0.f); v1 = fmaxf(v1, 0.f); v2 = fmaxf(v2, 0.f); }
    float m = (v0 + v1 + v2) * (1.0f / 3.0f);
    if (OUTER_RELU) m = fmaxf(m, 0.f);
    out[d * 32 + lane] = m;
}

// ---------------- launch ----------------

extern "C" void kernel_launch(void* const* d_in, const int* in_sizes, int n_in,
                              void* d_out, int out_size, void* d_ws, size_t ws_size,
                              hipStream_t stream) {
    const float* x       = (const float*)d_in[0];
    const int*   edge    = (const int*)  d_in[1];
    const float* w1_init = (const float*)d_in[2];
    const float* w1      = (const float*)d_in[3];
    const float* w1_root = (const float*)d_in[4];
    const float* b1      = (const float*)d_in[5];
    const float* w2_init = (const float*)d_in[6];
    const float* w2      = (const float*)d_in[7];
    const float* w2_root = (const float*)d_in[8];
    const float* b2      = (const float*)d_in[9];
    float* out = (float*)d_out;

    const int N = in_sizes[0] / 64;
    const int E = in_sizes[1] / 2;
    const int* src = edge;
    const int* dst = edge + E;

    // workspace carve (256B aligned)
    char* p = (char*)d_ws;
    auto alloc = [&](size_t bytes) { void* r = (void*)p; p += (bytes + 255) & ~(size_t)255; return r; };
    int*   deg      = (int*)  alloc((size_t)N * 4);
    float* dinv     = (float*)alloc((size_t)N * 4);
    int*   offsets  = (int*)  alloc((size_t)(N + 1) * 4);
    int*   cursor   = (int*)  alloc((size_t)N * 4);
    const int nScanBlocks = (N + 511) / 512;
    int*   bsums    = (int*)  alloc((size_t)nScanBlocks * 4);
    int*   csr_src  = (int*)  alloc((size_t)E * 4);
    bf16*  gatherA  = (bf16*) alloc((size_t)N * FDIM * 2);
    bf16*  gatherB  = (bf16*) alloc((size_t)N * FDIM * 2);
    float* rootb    = (float*)alloc((size_t)N * FDIM * 4);
    float* hbuf     = (float*)alloc((size_t)N * DIM * 4);
    (void)ws_size; (void)n_in; (void)out_size;

    const int gN   = (N + 255) / 256;
    const int gE   = (E + 255) / 256;
    const int gNod = (N + 7) / 8;        // 8 nodes per 256-thread block

    // ---- graph structure (rebuilt every call; deterministic topology) ----
    zero_int_kernel<<<gN, 256, 0, stream>>>(deg, N);
    count_deg_kernel<<<gE, 256, 0, stream>>>(dst, deg, E);
    dinv_kernel<<<gN, 256, 0, stream>>>(deg, dinv, N);
    scan1_kernel<<<nScanBlocks, 512, 0, stream>>>(deg, offsets, bsums, N);
    scan2_kernel<<<1, 64, 0, stream>>>(bsums, nScanBlocks);
    scan3_kernel<<<gN, 256, 0, stream>>>(offsets, cursor, bsums, N, E);
    fill_csr_kernel<<<gE, 256, 0, stream>>>(src, dst, cursor, csr_src, E);

    // ---- layer 1 (act = relu) ----
    mm_init_kernel<64><<<gNod, 256, 0, stream>>>(x, w1_init, w1_root, dinv, gatherA, rootb, N);
    prop_mm_kernel<true><<<gNod, 256, 0, stream>>>(gatherA, offsets, csr_src, dinv, rootb, b1, w1, gatherB, N);
    prop_mean_kernel<true, true><<<gNod, 256, 0, stream>>>(gatherB, offsets, csr_src, dinv, rootb, b1, hbuf, N);

    // ---- layer 2 (act = identity) ----
    mm_init_kernel<32><<<gNod, 256, 0, stream>>>(hbuf, w2_init, w2_root, dinv, gatherA, rootb, N);
    prop_mm_kernel<false><<<gNod, 256, 0, stream>>>(gatherA, offsets, csr_src, dinv, rootb, b2, w2, gatherB, N);
    prop_mean_kernel<false, false><<<gNod, 256, 0, stream>>>(gatherB, offsets, csr_src, dinv, rootb, b2, out, N);
}

// Round 3
// 662.878 us; speedup vs baseline: 1.3470x; 1.2310x over previous
//
#include <hip/hip_runtime.h>
#include <hip/hip_bf16.h>

// ARMA GNN (K=3 stacks, T=2 layers, F_in=64, DIM=32) on MI355X.
// Round 3: unroll-by-4 gather loops (12 loads in flight) to attack the
// latency-bound random gather; csr stores row offsets (src*FDIM).

#define KSTACK 3
#define DIM    32
#define FDIM   96   // KSTACK*DIM

typedef __hip_bfloat16 bf16;

// ---------------- CSR build ----------------

__global__ void zero_int_kernel(int* __restrict__ p, int n) {
    int i = blockIdx.x * 256 + threadIdx.x;
    if (i < n) p[i] = 0;
}

__global__ void count_deg_kernel(const int* __restrict__ dst, int* __restrict__ deg, int E) {
    int i = blockIdx.x * 256 + threadIdx.x;
    if (i < E) atomicAdd(&deg[dst[i]], 1);
}

__global__ void dinv_kernel(const int* __restrict__ deg, float* __restrict__ dinv, int N) {
    int i = blockIdx.x * 256 + threadIdx.x;
    if (i < N) {
        int d = deg[i];
        dinv[i] = (d > 0) ? rsqrtf((float)d) : 0.0f;
    }
}

__global__ __launch_bounds__(512) void scan1_kernel(const int* __restrict__ deg,
                                                    int* __restrict__ offsets,
                                                    int* __restrict__ bsums, int N) {
    __shared__ int tmp[512];
    int t = threadIdx.x;
    int i = blockIdx.x * 512 + t;
    int v = (i < N) ? deg[i] : 0;
    tmp[t] = v;
    __syncthreads();
    for (int off = 1; off < 512; off <<= 1) {
        int add = (t >= off) ? tmp[t - off] : 0;
        __syncthreads();
        tmp[t] += add;
        __syncthreads();
    }
    if (i < N) offsets[i] = tmp[t] - v;          // block-local exclusive
    if (t == 511) bsums[blockIdx.x] = tmp[511];  // block total
}

__global__ void scan2_kernel(int* __restrict__ bsums, int nb) {
    if (blockIdx.x == 0 && threadIdx.x == 0) {
        int run = 0;
        for (int b = 0; b < nb; ++b) { int v = bsums[b]; bsums[b] = run; run += v; }
    }
}

__global__ void scan3_kernel(int* __restrict__ offsets, int* __restrict__ cursor,
                             const int* __restrict__ bsums, int N, int E) {
    int i = blockIdx.x * 256 + threadIdx.x;
    if (i < N) {
        int v = offsets[i] + bsums[i >> 9];
        offsets[i] = v;
        cursor[i]  = v;
    }
    if (i == 0) offsets[N] = E;
}

__global__ void fill_csr_kernel(const int* __restrict__ src, const int* __restrict__ dst,
                                int* __restrict__ cursor, int* __restrict__ csr_off, int E) {
    int e = blockIdx.x * 256 + threadIdx.x;
    if (e < E) {
        int s = src[e], d = dst[e];
        int pos = atomicAdd(&cursor[d], 1);
        csr_off[pos] = s * FDIM;   // pre-scaled row offset
    }
}

// ---------------- gather core (unroll x4, 12 loads in flight) ----------------

__device__ __forceinline__ void gather3(const bf16* __restrict__ in,
                                        const int* __restrict__ csr_off,
                                        int s0, int s1, int lane,
                                        float& r0, float& r1, float& r2) {
    float a0 = 0.f, a1 = 0.f, a2 = 0.f;
    float b0 = 0.f, b1 = 0.f, b2 = 0.f;
    int i = s0;
    for (; i + 4 <= s1; i += 4) {
        const int o0 = csr_off[i], o1 = csr_off[i + 1], o2 = csr_off[i + 2], o3 = csr_off[i + 3];
        const bf16* p0 = in + o0;
        const bf16* p1 = in + o1;
        const bf16* p2 = in + o2;
        const bf16* p3 = in + o3;
        float x00 = __bfloat162float(p0[lane]), x01 = __bfloat162float(p0[32 + lane]), x02 = __bfloat162float(p0[64 + lane]);
        float x10 = __bfloat162float(p1[lane]), x11 = __bfloat162float(p1[32 + lane]), x12 = __bfloat162float(p1[64 + lane]);
        float x20 = __bfloat162float(p2[lane]), x21 = __bfloat162float(p2[32 + lane]), x22 = __bfloat162float(p2[64 + lane]);
        float x30 = __bfloat162float(p3[lane]), x31 = __bfloat162float(p3[32 + lane]), x32 = __bfloat162float(p3[64 + lane]);
        a0 += x00 + x20; a1 += x01 + x21; a2 += x02 + x22;
        b0 += x10 + x30; b1 += x11 + x31; b2 += x12 + x32;
    }
    for (; i < s1; ++i) {
        const bf16* p = in + csr_off[i];
        a0 += __bfloat162float(p[lane]);
        a1 += __bfloat162float(p[32 + lane]);
        a2 += __bfloat162float(p[64 + lane]);
    }
    r0 = a0 + b0; r1 = a1 + b1; r2 = a2 + b2;
}

// ---------------- init GEMM ----------------
// outA[n][k*32+o] = dinv[n] * sum_f x[n][f]*wA[k][f][o]   (bf16, pre-scaled gather row)
// outB[n][k*32+o] = sum_f x[n][f]*wB[k][f][o]             (fp32 root term)
template <int FIN>
__global__ __launch_bounds__(256) void mm_init_kernel(
    const float* __restrict__ x,    // [N, FIN]
    const float* __restrict__ wA,   // [K, FIN, 32]
    const float* __restrict__ wB,   // [K, FIN, 32]
    const float* __restrict__ dinv, // [N]
    bf16*  __restrict__ outA,       // [N, 96]
    float* __restrict__ outB,       // [N, 96]
    int N)
{
    __shared__ float swA[KSTACK * FIN * 32];
    __shared__ float swB[KSTACK * FIN * 32];
    __shared__ float sx[8 * FIN];
    const int tid = threadIdx.x;
    for (int i = tid; i < KSTACK * FIN * 32; i += 256) { swA[i] = wA[i]; swB[i] = wB[i]; }
    const int n0 = blockIdx.x * 8;
    for (int i = tid; i < 8 * FIN; i += 256) {
        int j = i / FIN, f = i % FIN;
        int n = n0 + j; if (n >= N) n = N - 1;
        sx[i] = x[(long)n * FIN + f];
    }
    __syncthreads();
    const int o = tid & 31;
    const int j = tid >> 5;
    const long n = n0 + j;
    if (n >= N) return;
    float accA[KSTACK] = {0.f, 0.f, 0.f};
    float accB[KSTACK] = {0.f, 0.f, 0.f};
    const float* xr = sx + j * FIN;
    #pragma unroll
    for (int f = 0; f < FIN; ++f) {
        float xv = xr[f];
        #pragma unroll
        for (int k = 0; k < KSTACK; ++k) {
            accA[k] += xv * swA[(k * FIN + f) * 32 + o];
            accB[k] += xv * swB[(k * FIN + f) * 32 + o];
        }
    }
    const float di = dinv[n];
    #pragma unroll
    for (int k = 0; k < KSTACK; ++k) {
        outA[n * FDIM + k * 32 + o] = __float2bfloat16(accA[k] * di);
        outB[n * FDIM + k * 32 + o] = accB[k];
    }
}

// ---------------- prop #1: gather + act + fused 32x32 GEMV, bf16-scaled out ----
template <bool RELU>
__global__ __launch_bounds__(256) void prop_mm_kernel(
    const bf16*  __restrict__ in,       // [N, 96] pre-scaled by dinv[src]
    const int*   __restrict__ offsets,  // [N+1]
    const int*   __restrict__ csr_off,  // [E] (src*FDIM)
    const float* __restrict__ dinv,     // [N]
    const float* __restrict__ root,     // [N, 96]
    const float* __restrict__ bias,     // [96]
    const float* __restrict__ w,        // [K,32,32]
    bf16* __restrict__ out, int N)
{
    __shared__ float sw[KSTACK * 32 * 32];
    __shared__ float sv[8][FDIM];
    const int tid = threadIdx.x;
    for (int i = tid; i < KSTACK * 32 * 32; i += 256) sw[i] = w[i];
    __syncthreads();
    const int lane = tid & 31;
    const int j    = tid >> 5;
    const long d   = (long)blockIdx.x * 8 + j;
    if (d >= N) return;
    const int s0 = offsets[d], s1 = offsets[d + 1];
    float a0, a1, a2;
    gather3(in, csr_off, s0, s1, lane, a0, a1, a2);
    const float di = dinv[d];
    float v0 = a0 * di + root[d * FDIM + lane]      + bias[lane];
    float v1 = a1 * di + root[d * FDIM + 32 + lane] + bias[32 + lane];
    float v2 = a2 * di + root[d * FDIM + 64 + lane] + bias[64 + lane];
    if (RELU) { v0 = fmaxf(v0, 0.f); v1 = fmaxf(v1, 0.f); v2 = fmaxf(v2, 0.f); }
    // per-half-wave LDS transpose: same wave writes then reads its own row -> no barrier
    sv[j][lane]      = v0;
    sv[j][32 + lane] = v1;
    sv[j][64 + lane] = v2;
    float o0 = 0.f, o1 = 0.f, o2 = 0.f;
    #pragma unroll
    for (int f = 0; f < 32; ++f) {
        o0 += sv[j][f]      * sw[(0 * 32 + f) * 32 + lane];
        o1 += sv[j][32 + f] * sw[(1 * 32 + f) * 32 + lane];
        o2 += sv[j][64 + f] * sw[(2 * 32 + f) * 32 + lane];
    }
    out[d * FDIM + lane]      = __float2bfloat16(o0 * di);
    out[d * FDIM + 32 + lane] = __float2bfloat16(o1 * di);
    out[d * FDIM + 64 + lane] = __float2bfloat16(o2 * di);
}

// ---------------- prop #2: gather + act + mean over stacks (fp32 out) -------
template <bool RELU, bool OUTER_RELU>
__global__ __launch_bounds__(256) void prop_mean_kernel(
    const bf16*  __restrict__ in,       // [N, 96] pre-scaled by dinv[src]
    const int*   __restrict__ offsets,
    const int*   __restrict__ csr_off,  // [E] (src*FDIM)
    const float* __restrict__ dinv,
    const float* __restrict__ root,     // [N, 96]
    const float* __restrict__ bias,     // [96]
    float* __restrict__ out,            // [N, 32]
    int N)
{
    const int lane = threadIdx.x & 31;
    const int j    = threadIdx.x >> 5;
    const long d   = (long)blockIdx.x * 8 + j;
    if (d >= N) return;
    const int s0 = offsets[d], s1 = offsets[d + 1];
    float a0, a1, a2;
    gather3(in, csr_off, s0, s1, lane, a0, a1, a2);
    const float di = dinv[d];
    float v0 = a0 * di + root[d * FDIM + lane]      + bias[lane];
    float v1 = a1 * di + root[d * FDIM + 32 + lane] + bias[32 + lane];
    float v2 = a2 * di + root[d * FDIM + 64 + lane] + bias[64 + lane];
    if (RELU) { v0 = fmaxf(v0, 0.f); v1 = fmaxf(v1, 0.f); v2 = fmaxf(v2, 0.f); }
    float m = (v0 + v1 + v2) * (1.0f / 3.0f);
    if (OUTER_RELU) m = fmaxf(m, 0.f);
    out[d * 32 + lane] = m;
}

// ---------------- launch ----------------

extern "C" void kernel_launch(void* const* d_in, const int* in_sizes, int n_in,
                              void* d_out, int out_size, void* d_ws, size_t ws_size,
                              hipStream_t stream) {
    const float* x       = (const float*)d_in[0];
    const int*   edge    = (const int*)  d_in[1];
    const float* w1_init = (const float*)d_in[2];
    const float* w1      = (const float*)d_in[3];
    const float* w1_root = (const float*)d_in[4];
    const float* b1      = (const float*)d_in[5];
    const float* w2_init = (const float*)d_in[6];
    const float* w2      = (const float*)d_in[7];
    const float* w2_root = (const float*)d_in[8];
    const float* b2      = (const float*)d_in[9];
    float* out = (float*)d_out;

    const int N = in_sizes[0] / 64;
    const int E = in_sizes[1] / 2;
    const int* src = edge;
    const int* dst = edge + E;

    // workspace carve (256B aligned)
    char* p = (char*)d_ws;
    auto alloc = [&](size_t bytes) { void* r = (void*)p; p += (bytes + 255) & ~(size_t)255; return r; };
    int*   deg      = (int*)  alloc((size_t)N * 4);
    float* dinv     = (float*)alloc((size_t)N * 4);
    int*   offsets  = (int*)  alloc((size_t)(N + 1) * 4);
    int*   cursor   = (int*)  alloc((size_t)N * 4);
    const int nScanBlocks = (N + 511) / 512;
    int*   bsums    = (int*)  alloc((size_t)nScanBlocks * 4);
    int*   csr_off  = (int*)  alloc((size_t)E * 4);
    bf16*  gatherA  = (bf16*) alloc((size_t)N * FDIM * 2);
    bf16*  gatherB  = (bf16*) alloc((size_t)N * FDIM * 2);
    float* rootb    = (float*)alloc((size_t)N * FDIM * 4);
    float* hbuf     = (float*)alloc((size_t)N * DIM * 4);
    (void)ws_size; (void)n_in; (void)out_size;

    const int gN   = (N + 255) / 256;
    const int gE   = (E + 255) / 256;
    const int gNod = (N + 7) / 8;        // 8 nodes per 256-thread block

    // ---- graph structure (rebuilt every call; deterministic topology) ----
    zero_int_kernel<<<gN, 256, 0, stream>>>(deg, N);
    count_deg_kernel<<<gE, 256, 0, stream>>>(dst, deg, E);
    dinv_kernel<<<gN, 256, 0, stream>>>(deg, dinv, N);
    scan1_kernel<<<nScanBlocks, 512, 0, stream>>>(deg, offsets, bsums, N);
    scan2_kernel<<<1, 64, 0, stream>>>(bsums, nScanBlocks);
    scan3_kernel<<<gN, 256, 0, stream>>>(offsets, cursor, bsums, N, E);
    fill_csr_kernel<<<gE, 256, 0, stream>>>(src, dst, cursor, csr_off, E);

    // ---- layer 1 (act = relu) ----
    mm_init_kernel<64><<<gNod, 256, 0, stream>>>(x, w1_init, w1_root, dinv, gatherA, rootb, N);
    prop_mm_kernel<true><<<gNod, 256, 0, stream>>>(gatherA, offsets, csr_off, dinv, rootb, b1, w1, gatherB, N);
    prop_mean_kernel<true, true><<<gNod, 256, 0, stream>>>(gatherB, offsets, csr_off, dinv, rootb, b1, hbuf, N);

    // ---- layer 2 (act = identity) ----
    mm_init_kernel<32><<<gNod, 256, 0, stream>>>(hbuf, w2_init, w2_root, dinv, gatherA, rootb, N);
    prop_mm_kernel<false><<<gNod, 256, 0, stream>>>(gatherA, offsets, csr_off, dinv, rootb, b2, w2, gatherB, N);
    prop_mean_kernel<false, false><<<gNod, 256, 0, stream>>>(gatherB, offsets, csr_off, dinv, rootb, b2, out, N);
}

// Round 4
// 633.961 us; speedup vs baseline: 1.4084x; 1.0456x over previous
//
#include <hip/hip_runtime.h>
#include <hip/hip_bf16.h>

// ARMA GNN (K=3 stacks, T=2 layers, F_in=64, DIM=32) on MI355X.
// Round 4: dwordx2 gather (1 load/edge/row), unroll x8, int4 offset loads,
// 4-aligned CSR segments padded with a dummy zero row (row N).

#define KSTACK 3
#define DIM    32
#define FDIM   96    // KSTACK*DIM
#define ROWB   192   // bytes per feature row (96 bf16)

typedef __hip_bfloat16 bf16;

// ---------------- CSR build ----------------

__global__ void zero_int_kernel(int* __restrict__ p, int n) {
    int i = blockIdx.x * 256 + threadIdx.x;
    if (i < n) p[i] = 0;
}

__global__ void count_deg_kernel(const int* __restrict__ dst, int* __restrict__ deg, int E) {
    int i = blockIdx.x * 256 + threadIdx.x;
    if (i < E) atomicAdd(&deg[dst[i]], 1);
}

__global__ void dinv_kernel(const int* __restrict__ deg, float* __restrict__ dinv, int N) {
    int i = blockIdx.x * 256 + threadIdx.x;
    if (i < N) {
        int d = deg[i];
        dinv[i] = (d > 0) ? rsqrtf((float)d) : 0.0f;
    }
}

// scans deg4 = roundup4(deg) over N+1 items (item N contributes 0)
__global__ __launch_bounds__(512) void scan1_kernel(const int* __restrict__ deg,
                                                    int* __restrict__ off4,
                                                    int* __restrict__ bsums, int N) {
    __shared__ int tmp[512];
    int t = threadIdx.x;
    int i = blockIdx.x * 512 + t;
    int v = (i < N) ? ((deg[i] + 3) & ~3) : 0;
    tmp[t] = v;
    __syncthreads();
    for (int off = 1; off < 512; off <<= 1) {
        int add = (t >= off) ? tmp[t - off] : 0;
        __syncthreads();
        tmp[t] += add;
        __syncthreads();
    }
    if (i <= N) off4[i] = tmp[t] - v;            // block-local exclusive
    if (t == 511) bsums[blockIdx.x] = tmp[511];  // block total
}

__global__ void scan2_kernel(int* __restrict__ bsums, int nb) {
    if (blockIdx.x == 0 && threadIdx.x == 0) {
        int run = 0;
        for (int b = 0; b < nb; ++b) { int v = bsums[b]; bsums[b] = run; run += v; }
    }
}

__global__ void scan3_kernel(int* __restrict__ off4, int* __restrict__ cursor,
                             const int* __restrict__ bsums, int N) {
    int i = blockIdx.x * 256 + threadIdx.x;
    if (i <= N) {
        int v = off4[i] + bsums[i >> 9];
        off4[i] = v;
        if (i < N) cursor[i] = v;
    }
}

__global__ void fill_default_kernel(int* __restrict__ csr, int total, int dummy_off) {
    int i = blockIdx.x * 256 + threadIdx.x;
    if (i < total) csr[i] = dummy_off;
}

__global__ void fill_csr_kernel(const int* __restrict__ src, const int* __restrict__ dst,
                                int* __restrict__ cursor, int* __restrict__ csr_boff, int E) {
    int e = blockIdx.x * 256 + threadIdx.x;
    if (e < E) {
        int s = src[e], d = dst[e];
        int pos = atomicAdd(&cursor[d], 1);
        csr_boff[pos] = s * ROWB;   // byte offset of source row
    }
}

// ---------------- gather helpers ----------------

__device__ __forceinline__ void bacc(unsigned int q, float& lo, float& hi) {
    lo += __uint_as_float(q << 16);
    hi += __uint_as_float(q & 0xffff0000u);
}

__device__ __forceinline__ void acc_row(const char* __restrict__ base, int boff, int lb,
                                        float& a0, float& a1, float& a2, float& a3) {
    uint2 q = *reinterpret_cast<const uint2*>(base + boff + lb);
    bacc(q.x, a0, a1);
    bacc(q.y, a2, a3);
}

// gather: lane l<24 accumulates features 4l..4l+3 of all source rows.
// (s1-s0) is a multiple of 4 (padded with dummy zero rows).
__device__ __forceinline__ void gather4(const char* __restrict__ base,
                                        const int* __restrict__ csr, int s0, int s1,
                                        int lb, bool ld,
                                        float& a0, float& a1, float& a2, float& a3) {
    int i = s0;
    for (; i + 8 <= s1; i += 8) {
        int4 oA = *reinterpret_cast<const int4*>(csr + i);
        int4 oB = *reinterpret_cast<const int4*>(csr + i + 4);
        if (ld) {
            uint2 q0 = *reinterpret_cast<const uint2*>(base + oA.x + lb);
            uint2 q1 = *reinterpret_cast<const uint2*>(base + oA.y + lb);
            uint2 q2 = *reinterpret_cast<const uint2*>(base + oA.z + lb);
            uint2 q3 = *reinterpret_cast<const uint2*>(base + oA.w + lb);
            uint2 q4 = *reinterpret_cast<const uint2*>(base + oB.x + lb);
            uint2 q5 = *reinterpret_cast<const uint2*>(base + oB.y + lb);
            uint2 q6 = *reinterpret_cast<const uint2*>(base + oB.z + lb);
            uint2 q7 = *reinterpret_cast<const uint2*>(base + oB.w + lb);
            bacc(q0.x, a0, a1); bacc(q0.y, a2, a3);
            bacc(q1.x, a0, a1); bacc(q1.y, a2, a3);
            bacc(q2.x, a0, a1); bacc(q2.y, a2, a3);
            bacc(q3.x, a0, a1); bacc(q3.y, a2, a3);
            bacc(q4.x, a0, a1); bacc(q4.y, a2, a3);
            bacc(q5.x, a0, a1); bacc(q5.y, a2, a3);
            bacc(q6.x, a0, a1); bacc(q6.y, a2, a3);
            bacc(q7.x, a0, a1); bacc(q7.y, a2, a3);
        }
    }
    if (i < s1) {  // exactly one 4-edge block
        int4 oA = *reinterpret_cast<const int4*>(csr + i);
        if (ld) {
            acc_row(base, oA.x, lb, a0, a1, a2, a3);
            acc_row(base, oA.y, lb, a0, a1, a2, a3);
            acc_row(base, oA.z, lb, a0, a1, a2, a3);
            acc_row(base, oA.w, lb, a0, a1, a2, a3);
        }
    }
}

// ---------------- init GEMM ----------------
// outA[n][k*32+o] = bf16(dinv[n] * sum_f x[n][f]*wA[k][f][o]); row N = zeros (dummy)
// outB[n][k*32+o] = sum_f x[n][f]*wB[k][f][o]   (fp32 root term, rows 0..N-1)
template <int FIN>
__global__ __launch_bounds__(256) void mm_init_kernel(
    const float* __restrict__ x,    // [N, FIN]
    const float* __restrict__ wA,   // [K, FIN, 32]
    const float* __restrict__ wB,   // [K, FIN, 32]
    const float* __restrict__ dinv, // [N]
    bf16*  __restrict__ outA,       // [N+1, 96]
    float* __restrict__ outB,       // [N, 96]
    int N)
{
    __shared__ float swA[KSTACK * FIN * 32];
    __shared__ float swB[KSTACK * FIN * 32];
    __shared__ float sx[8 * FIN];
    const int tid = threadIdx.x;
    for (int i = tid; i < KSTACK * FIN * 32; i += 256) { swA[i] = wA[i]; swB[i] = wB[i]; }
    const int n0 = blockIdx.x * 8;
    for (int i = tid; i < 8 * FIN; i += 256) {
        int j = i / FIN, f = i % FIN;
        int n = n0 + j; if (n >= N) n = N - 1;
        sx[i] = x[(long)n * FIN + f];
    }
    __syncthreads();
    const int o = tid & 31;
    const int j = tid >> 5;
    const long n = n0 + j;
    if (n > N) return;
    if (n == N) {   // dummy zero row for CSR padding
        bf16 z = __float2bfloat16(0.f);
        #pragma unroll
        for (int k = 0; k < KSTACK; ++k) outA[n * FDIM + k * 32 + o] = z;
        return;
    }
    float accA[KSTACK] = {0.f, 0.f, 0.f};
    float accB[KSTACK] = {0.f, 0.f, 0.f};
    const float* xr = sx + j * FIN;
    #pragma unroll
    for (int f = 0; f < FIN; ++f) {
        float xv = xr[f];
        #pragma unroll
        for (int k = 0; k < KSTACK; ++k) {
            accA[k] += xv * swA[(k * FIN + f) * 32 + o];
            accB[k] += xv * swB[(k * FIN + f) * 32 + o];
        }
    }
    const float di = dinv[n];
    #pragma unroll
    for (int k = 0; k < KSTACK; ++k) {
        outA[n * FDIM + k * 32 + o] = __float2bfloat16(accA[k] * di);
        outB[n * FDIM + k * 32 + o] = accB[k];
    }
}

// ---------------- prop #1: gather + act + fused 32x32 GEMV ----------------
template <bool RELU>
__global__ __launch_bounds__(256) void prop_mm_kernel(
    const bf16*  __restrict__ in,       // [N+1, 96] pre-scaled by dinv[src]
    const int*   __restrict__ off4,     // [N+1]
    const int*   __restrict__ csr,      // byte row offsets, 4-aligned segments
    const float* __restrict__ dinv,
    const float* __restrict__ root,     // [N, 96]
    const float* __restrict__ bias,     // [96]
    const float* __restrict__ w,        // [K,32,32]
    bf16* __restrict__ out, int N)      // [N+1, 96]; row N zeroed
{
    __shared__ float sw[KSTACK * 32 * 32];
    __shared__ float sv[8][FDIM];
    const int tid = threadIdx.x;
    for (int i = tid; i < KSTACK * 32 * 32; i += 256) sw[i] = w[i];
    __syncthreads();
    const int lane = tid & 31;
    const int j    = tid >> 5;
    const long d   = (long)blockIdx.x * 8 + j;
    if (d > N) return;
    if (d == N) {   // keep dummy row zero
        bf16 z = __float2bfloat16(0.f);
        out[d * FDIM + lane] = z;
        out[d * FDIM + 32 + lane] = z;
        out[d * FDIM + 64 + lane] = z;
        return;
    }
    const int s0 = off4[d], s1 = off4[d + 1];
    const bool ld = lane < 24;
    const int  lb = lane * 8;
    float a0 = 0.f, a1 = 0.f, a2 = 0.f, a3 = 0.f;
    gather4((const char*)in, csr, s0, s1, lb, ld, a0, a1, a2, a3);
    const float di = dinv[d];
    if (ld) {
        float4 r4 = *reinterpret_cast<const float4*>(root + d * FDIM + 4 * lane);
        float4 b4 = *reinterpret_cast<const float4*>(bias + 4 * lane);
        float v0 = a0 * di + r4.x + b4.x;
        float v1 = a1 * di + r4.y + b4.y;
        float v2 = a2 * di + r4.z + b4.z;
        float v3 = a3 * di + r4.w + b4.w;
        if (RELU) {
            v0 = fmaxf(v0, 0.f); v1 = fmaxf(v1, 0.f);
            v2 = fmaxf(v2, 0.f); v3 = fmaxf(v3, 0.f);
        }
        sv[j][4 * lane]     = v0;
        sv[j][4 * lane + 1] = v1;
        sv[j][4 * lane + 2] = v2;
        sv[j][4 * lane + 3] = v3;
    }
    // same-wave LDS write->read: no barrier needed
    float o0 = 0.f, o1 = 0.f, o2 = 0.f;
    #pragma unroll
    for (int f = 0; f < 32; ++f) {
        o0 += sv[j][f]      * sw[f * 32 + lane];
        o1 += sv[j][32 + f] * sw[(32 + f) * 32 + lane];
        o2 += sv[j][64 + f] * sw[(64 + f) * 32 + lane];
    }
    out[d * FDIM + lane]      = __float2bfloat16(o0 * di);
    out[d * FDIM + 32 + lane] = __float2bfloat16(o1 * di);
    out[d * FDIM + 64 + lane] = __float2bfloat16(o2 * di);
}

// ---------------- prop #2: gather + act + mean over stacks -------------
template <bool RELU, bool OUTER_RELU>
__global__ __launch_bounds__(256) void prop_mean_kernel(
    const bf16*  __restrict__ in,       // [N+1, 96] pre-scaled by dinv[src]
    const int*   __restrict__ off4,
    const int*   __restrict__ csr,
    const float* __restrict__ dinv,
    const float* __restrict__ root,     // [N, 96]
    const float* __restrict__ bias,     // [96]
    float* __restrict__ out,            // [N, 32]
    int N)
{
    __shared__ float sv[8][FDIM];
    const int lane = threadIdx.x & 31;
    const int j    = threadIdx.x >> 5;
    const long d   = (long)blockIdx.x * 8 + j;
    if (d >= N) return;
    const int s0 = off4[d], s1 = off4[d + 1];
    const bool ld = lane < 24;
    const int  lb = lane * 8;
    float a0 = 0.f, a1 = 0.f, a2 = 0.f, a3 = 0.f;
    gather4((const char*)in, csr, s0, s1, lb, ld, a0, a1, a2, a3);
    const float di = dinv[d];
    if (ld) {
        float4 r4 = *reinterpret_cast<const float4*>(root + d * FDIM + 4 * lane);
        float4 b4 = *reinterpret_cast<const float4*>(bias + 4 * lane);
        float v0 = a0 * di + r4.x + b4.x;
        float v1 = a1 * di + r4.y + b4.y;
        float v2 = a2 * di + r4.z + b4.z;
        float v3 = a3 * di + r4.w + b4.w;
        if (RELU) {
            v0 = fmaxf(v0, 0.f); v1 = fmaxf(v1, 0.f);
            v2 = fmaxf(v2, 0.f); v3 = fmaxf(v3, 0.f);
        }
        sv[j][4 * lane]     = v0;
        sv[j][4 * lane + 1] = v1;
        sv[j][4 * lane + 2] = v2;
        sv[j][4 * lane + 3] = v3;
    }
    float m = (sv[j][lane] + sv[j][32 + lane] + sv[j][64 + lane]) * (1.0f / 3.0f);
    if (OUTER_RELU) m = fmaxf(m, 0.f);
    out[d * 32 + lane] = m;
}

// ---------------- launch ----------------

extern "C" void kernel_launch(void* const* d_in, const int* in_sizes, int n_in,
                              void* d_out, int out_size, void* d_ws, size_t ws_size,
                              hipStream_t stream) {
    const float* x       = (const float*)d_in[0];
    const int*   edge    = (const int*)  d_in[1];
    const float* w1_init = (const float*)d_in[2];
    const float* w1      = (const float*)d_in[3];
    const float* w1_root = (const float*)d_in[4];
    const float* b1      = (const float*)d_in[5];
    const float* w2_init = (const float*)d_in[6];
    const float* w2      = (const float*)d_in[7];
    const float* w2_root = (const float*)d_in[8];
    const float* b2      = (const float*)d_in[9];
    float* out = (float*)d_out;

    const int N = in_sizes[0] / 64;
    const int E = in_sizes[1] / 2;
    const int* src = edge;
    const int* dst = edge + E;
    const int E4max = E + 3 * N;   // upper bound on padded CSR length

    // workspace carve (256B aligned)
    char* p = (char*)d_ws;
    auto alloc = [&](size_t bytes) { void* r = (void*)p; p += (bytes + 255) & ~(size_t)255; return r; };
    int*   deg      = (int*)  alloc((size_t)N * 4);
    float* dinv     = (float*)alloc((size_t)N * 4);
    int*   off4     = (int*)  alloc((size_t)(N + 1) * 4);
    int*   cursor   = (int*)  alloc((size_t)N * 4);
    const int nScanBlocks = (N + 1 + 511) / 512;
    int*   bsums    = (int*)  alloc((size_t)nScanBlocks * 4);
    int*   csr_boff = (int*)  alloc((size_t)(E4max + 64) * 4);
    bf16*  gatherA  = (bf16*) alloc((size_t)(N + 1) * FDIM * 2);
    bf16*  gatherB  = (bf16*) alloc((size_t)(N + 1) * FDIM * 2);
    float* rootb    = (float*)alloc((size_t)N * FDIM * 4);
    float* hbuf     = (float*)alloc((size_t)N * DIM * 4);
    (void)ws_size; (void)n_in; (void)out_size;

    const int gN    = (N + 255) / 256;
    const int gN1   = (N + 1 + 255) / 256;
    const int gE    = (E + 255) / 256;
    const int gE4   = (E4max + 255) / 256;
    const int gNod  = (N + 7) / 8;       // 8 dst per 256-thread block
    const int gNod1 = (N + 8) / 8;       // includes dummy row N

    // ---- graph structure (rebuilt every call; deterministic topology) ----
    zero_int_kernel<<<gN, 256, 0, stream>>>(deg, N);
    count_deg_kernel<<<gE, 256, 0, stream>>>(dst, deg, E);
    dinv_kernel<<<gN, 256, 0, stream>>>(deg, dinv, N);
    scan1_kernel<<<nScanBlocks, 512, 0, stream>>>(deg, off4, bsums, N);
    scan2_kernel<<<1, 64, 0, stream>>>(bsums, nScanBlocks);
    scan3_kernel<<<gN1, 256, 0, stream>>>(off4, cursor, bsums, N);
    fill_default_kernel<<<gE4, 256, 0, stream>>>(csr_boff, E4max, N * ROWB);
    fill_csr_kernel<<<gE, 256, 0, stream>>>(src, dst, cursor, csr_boff, E);

    // ---- layer 1 (act = relu) ----
    mm_init_kernel<64><<<gNod1, 256, 0, stream>>>(x, w1_init, w1_root, dinv, gatherA, rootb, N);
    prop_mm_kernel<true><<<gNod1, 256, 0, stream>>>(gatherA, off4, csr_boff, dinv, rootb, b1, w1, gatherB, N);
    prop_mean_kernel<true, true><<<gNod, 256, 0, stream>>>(gatherB, off4, csr_boff, dinv, rootb, b1, hbuf, N);

    // ---- layer 2 (act = identity) ----
    mm_init_kernel<32><<<gNod1, 256, 0, stream>>>(hbuf, w2_init, w2_root, dinv, gatherA, rootb, N);
    prop_mm_kernel<false><<<gNod1, 256, 0, stream>>>(gatherA, off4, csr_boff, dinv, rootb, b2, w2, gatherB, N);
    prop_mean_kernel<false, false><<<gNod, 256, 0, stream>>>(gatherB, off4, csr_boff, dinv, rootb, b2, out, N);
}

// Round 5
// 589.095 us; speedup vs baseline: 1.5157x; 1.0762x over previous
//
#include <hip/hip_runtime.h>
#include <hip/hip_bf16.h>

// ARMA GNN (K=3 stacks, T=2 layers, F_in=64, DIM=32) on MI355X.
// Round 5: (a) two-phase bucketed edge grouping kills fill_csr's 16x write
// amplification; (b) dual-dst gather chains (8 rows in flight / 32-lane group)
// with dummy-row predication; root/bias hoisted above the gather loop.

#define KSTACK 3
#define DIM    32
#define FDIM   96    // KSTACK*DIM
#define ROWB   192   // bytes per feature row (96 bf16)
#define NB     256   // dst buckets (dst>>9; N<=131072)
#define TILE   4096  // edges per grouping block

typedef __hip_bfloat16 bf16;

// ---------------- CSR build ----------------

__global__ void zero_int_kernel(int* __restrict__ p, int n) {
    int i = blockIdx.x * 256 + threadIdx.x;
    if (i < n) p[i] = 0;
}

__global__ void count_deg_kernel(const int* __restrict__ dst, int* __restrict__ deg, int E) {
    int i = blockIdx.x * 256 + threadIdx.x;
    if (i < E) atomicAdd(&deg[dst[i]], 1);
}

__global__ void dinv_kernel(const int* __restrict__ deg, float* __restrict__ dinv, int N) {
    int i = blockIdx.x * 256 + threadIdx.x;
    if (i < N) {
        int d = deg[i];
        dinv[i] = (d > 0) ? rsqrtf((float)d) : 0.0f;
    }
}

// scans deg4 = roundup4(deg) over N+1 items (item N contributes 0)
__global__ __launch_bounds__(512) void scan1_kernel(const int* __restrict__ deg,
                                                    int* __restrict__ off4,
                                                    int* __restrict__ bsums, int N) {
    __shared__ int tmp[512];
    int t = threadIdx.x;
    int i = blockIdx.x * 512 + t;
    int v = (i < N) ? ((deg[i] + 3) & ~3) : 0;
    tmp[t] = v;
    __syncthreads();
    for (int off = 1; off < 512; off <<= 1) {
        int add = (t >= off) ? tmp[t - off] : 0;
        __syncthreads();
        tmp[t] += add;
        __syncthreads();
    }
    if (i <= N) off4[i] = tmp[t] - v;            // block-local exclusive
    if (t == 511) bsums[blockIdx.x] = tmp[511];  // block total
}

__global__ void scan2_kernel(int* __restrict__ bsums, int nb) {
    if (blockIdx.x == 0 && threadIdx.x == 0) {
        int run = 0;
        for (int b = 0; b < nb; ++b) { int v = bsums[b]; bsums[b] = run; run += v; }
    }
}

__global__ void scan3_kernel(int* __restrict__ off4, int* __restrict__ cursor,
                             const int* __restrict__ bsums, int N) {
    int i = blockIdx.x * 256 + threadIdx.x;
    if (i <= N) {
        int v = off4[i] + bsums[i >> 9];
        off4[i] = v;
        if (i < N) cursor[i] = v;
    }
}

// per-bucket edge counts from deg (bucket = 512 consecutive nodes)
__global__ __launch_bounds__(256) void bucket_sum_kernel(const int* __restrict__ deg,
                                                         int* __restrict__ bcnt, int N) {
    __shared__ int s[256];
    const int b = blockIdx.x, t = threadIdx.x;
    int i0 = b * 512 + t;
    int v = 0;
    if (i0 < N) v += deg[i0];
    if (i0 + 256 < N) v += deg[i0 + 256];
    s[t] = v;
    __syncthreads();
    for (int off = 128; off > 0; off >>= 1) {
        if (t < off) s[t] += s[t + off];
        __syncthreads();
    }
    if (t == 0) bcnt[b] = s[0];
}

__global__ __launch_bounds__(256) void bucket_scan_kernel(const int* __restrict__ bcnt,
                                                          int* __restrict__ gcur) {
    __shared__ int s[NB];
    const int t = threadIdx.x;
    int v = bcnt[t];
    s[t] = v;
    __syncthreads();
    for (int off = 1; off < NB; off <<= 1) {
        int add = (t >= off) ? s[t - off] : 0;
        __syncthreads();
        s[t] += add;
        __syncthreads();
    }
    gcur[t] = s[t] - v;   // exclusive base; doubles as global cursor
}

// counting-sort pass: group edges by dst>>9 with coalesced output writes
__global__ __launch_bounds__(256) void group_edges_kernel(
    const int* __restrict__ src, const int* __restrict__ dst,
    int* __restrict__ gcur, int2* __restrict__ grouped, int E)
{
    __shared__ int cnt[NB], pref[NB], lbase[NB], lofs[NB], gres[NB];
    __shared__ int2 stage[TILE];
    const int tid = threadIdx.x;
    const int e0 = blockIdx.x * TILE;
    const int count = min(TILE, E - e0);
    cnt[tid] = 0;
    __syncthreads();
    #pragma unroll
    for (int u = 0; u < TILE / 256; ++u) {
        int idx = u * 256 + tid;
        if (idx < count) atomicAdd(&cnt[dst[e0 + idx] >> 9], 1);
    }
    __syncthreads();
    int v = cnt[tid];
    pref[tid] = v;
    __syncthreads();
    for (int off = 1; off < NB; off <<= 1) {
        int add = (tid >= off) ? pref[tid - off] : 0;
        __syncthreads();
        pref[tid] += add;
        __syncthreads();
    }
    int ex = pref[tid] - v;
    lbase[tid] = ex;
    lofs[tid]  = ex;
    gres[tid] = atomicAdd(&gcur[tid], v);   // reserve global chunk for this block
    __syncthreads();
    #pragma unroll
    for (int u = 0; u < TILE / 256; ++u) {
        int idx = u * 256 + tid;
        if (idx < count) {
            int e = e0 + idx;
            int d = dst[e];
            int lp = atomicAdd(&lofs[d >> 9], 1);
            stage[lp] = make_int2(src[e] * ROWB, d);
        }
    }
    __syncthreads();
    for (int i = tid; i < count; i += 256) {
        int2 pr = stage[i];
        int b = pr.y >> 9;
        grouped[gres[b] + (i - lbase[b])] = pr;   // coalesced runs per bucket
    }
}

// fill CSR from bucket-grouped edges: scatter now hits ~32KB L2-local windows
__global__ void fill_csr_kernel(const int2* __restrict__ grouped, int* __restrict__ cursor,
                                int* __restrict__ csr_boff, int E) {
    int e = blockIdx.x * 256 + threadIdx.x;
    if (e < E) {
        int2 pr = grouped[e];
        int pos = atomicAdd(&cursor[pr.y], 1);
        csr_boff[pos] = pr.x;
    }
}

// write dummy-row offsets into the 0-3 pad slots of each node's segment
__global__ void pad_csr_kernel(const int* __restrict__ off4, const int* __restrict__ deg,
                               int* __restrict__ csr_boff, int N, int dummy) {
    int i = blockIdx.x * 256 + threadIdx.x;
    if (i < N) {
        int p = off4[i] + deg[i];
        int e = off4[i + 1];
        for (; p < e; ++p) csr_boff[p] = dummy;
    }
}

__global__ void zero_dummy_kernel(bf16* __restrict__ a, bf16* __restrict__ b, int N) {
    int t = threadIdx.x;
    if (t < FDIM) {
        bf16 z = __float2bfloat16(0.f);
        a[(long)N * FDIM + t] = z;
        b[(long)N * FDIM + t] = z;
    }
}

// ---------------- init GEMM ----------------
template <int FIN>
__global__ __launch_bounds__(256) void mm_init_kernel(
    const float* __restrict__ x,    // [N, FIN]
    const float* __restrict__ wA,   // [K, FIN, 32]
    const float* __restrict__ wB,   // [K, FIN, 32]
    const float* __restrict__ dinv, // [N]
    bf16*  __restrict__ outA,       // [N+1, 96] (row N maintained elsewhere)
    float* __restrict__ outB,       // [N, 96]
    int N)
{
    __shared__ float swA[KSTACK * FIN * 32];
    __shared__ float swB[KSTACK * FIN * 32];
    __shared__ float sx[8 * FIN];
    const int tid = threadIdx.x;
    for (int i = tid; i < KSTACK * FIN * 32; i += 256) { swA[i] = wA[i]; swB[i] = wB[i]; }
    const int n0 = blockIdx.x * 8;
    for (int i = tid; i < 8 * FIN; i += 256) {
        int j = i / FIN, f = i % FIN;
        int n = n0 + j; if (n >= N) n = N - 1;
        sx[i] = x[(long)n * FIN + f];
    }
    __syncthreads();
    const int o = tid & 31;
    const int j = tid >> 5;
    const long n = n0 + j;
    if (n >= N) return;
    float accA[KSTACK] = {0.f, 0.f, 0.f};
    float accB[KSTACK] = {0.f, 0.f, 0.f};
    const float* xr = sx + j * FIN;
    #pragma unroll
    for (int f = 0; f < FIN; ++f) {
        float xv = xr[f];
        #pragma unroll
        for (int k = 0; k < KSTACK; ++k) {
            accA[k] += xv * swA[(k * FIN + f) * 32 + o];
            accB[k] += xv * swB[(k * FIN + f) * 32 + o];
        }
    }
    const float di = dinv[n];
    #pragma unroll
    for (int k = 0; k < KSTACK; ++k) {
        outA[n * FDIM + k * 32 + o] = __float2bfloat16(accA[k] * di);
        outB[n * FDIM + k * 32 + o] = accB[k];
    }
}

// ---------------- gather helpers ----------------

__device__ __forceinline__ void bacc(unsigned int q, float& lo, float& hi) {
    lo += __uint_as_float(q << 16);
    hi += __uint_as_float(q & 0xffff0000u);
}

// dual-dst gather: 8 independent row loads in flight per 32-lane group.
// Out-of-range rows are predicated to the dummy zero row (offset `dummy`).
#define GATHER_LOOP()                                                          \
    const int m = max(nA, nB);                                                 \
    float aA0=0.f,aA1=0.f,aA2=0.f,aA3=0.f;                                     \
    float aB0=0.f,aB1=0.f,aB2=0.f,aB3=0.f;                                     \
    for (int b = 0; b < m; b += 4) {                                           \
        int4 tA = *reinterpret_cast<const int4*>(csr + iA + b);                \
        int4 tB = *reinterpret_cast<const int4*>(csr + iB + b);                \
        const int rA = nA - b, rB = nB - b;                                    \
        int oA0 = rA > 0 ? tA.x : dummy;                                       \
        int oA1 = rA > 1 ? tA.y : dummy;                                       \
        int oA2 = rA > 2 ? tA.z : dummy;                                       \
        int oA3 = rA > 3 ? tA.w : dummy;                                       \
        int oB0 = rB > 0 ? tB.x : dummy;                                       \
        int oB1 = rB > 1 ? tB.y : dummy;                                       \
        int oB2 = rB > 2 ? tB.z : dummy;                                       \
        int oB3 = rB > 3 ? tB.w : dummy;                                       \
        if (ld) {                                                              \
            uint2 qA0 = *reinterpret_cast<const uint2*>(base + oA0 + lb);      \
            uint2 qA1 = *reinterpret_cast<const uint2*>(base + oA1 + lb);      \
            uint2 qA2 = *reinterpret_cast<const uint2*>(base + oA2 + lb);      \
            uint2 qA3 = *reinterpret_cast<const uint2*>(base + oA3 + lb);      \
            uint2 qB0 = *reinterpret_cast<const uint2*>(base + oB0 + lb);      \
            uint2 qB1 = *reinterpret_cast<const uint2*>(base + oB1 + lb);      \
            uint2 qB2 = *reinterpret_cast<const uint2*>(base + oB2 + lb);      \
            uint2 qB3 = *reinterpret_cast<const uint2*>(base + oB3 + lb);      \
            bacc(qA0.x,aA0,aA1); bacc(qA0.y,aA2,aA3);                          \
            bacc(qA1.x,aA0,aA1); bacc(qA1.y,aA2,aA3);                          \
            bacc(qA2.x,aA0,aA1); bacc(qA2.y,aA2,aA3);                          \
            bacc(qA3.x,aA0,aA1); bacc(qA3.y,aA2,aA3);                          \
            bacc(qB0.x,aB0,aB1); bacc(qB0.y,aB2,aB3);                          \
            bacc(qB1.x,aB0,aB1); bacc(qB1.y,aB2,aB3);                          \
            bacc(qB2.x,aB0,aB1); bacc(qB2.y,aB2,aB3);                          \
            bacc(qB3.x,aB0,aB1); bacc(qB3.y,aB2,aB3);                          \
        }                                                                      \
    }

// ---------------- prop #1: gather + act + fused 32x32 GEMV ----------------
template <bool RELU>
__global__ __launch_bounds__(256) void prop_mm_kernel(
    const bf16*  __restrict__ in,       // [N+1, 96] pre-scaled by dinv[src]
    const int*   __restrict__ off4,     // [N+1]
    const int*   __restrict__ csr,      // byte row offsets, 4-aligned segments
    const float* __restrict__ dinv,
    const float* __restrict__ root,     // [N, 96]
    const float* __restrict__ bias,     // [96]
    const float* __restrict__ w,        // [K,32,32]
    bf16* __restrict__ out, int N)      // [N+1, 96]; row N maintained elsewhere
{
    __shared__ float sw[KSTACK * 32 * 32];
    __shared__ float sv[16][FDIM];
    const int tid = threadIdx.x;
    for (int i = tid; i < KSTACK * 32 * 32; i += 256) sw[i] = w[i];
    __syncthreads();
    const int lane = tid & 31;
    const int j    = tid >> 5;
    const int dA   = blockIdx.x * 16 + j;
    const int dB   = dA + 8;
    const int dummy = N * ROWB;
    const bool ld  = lane < 24;
    const int  lb  = lane * 8;
    const int  fo  = ld ? 4 * lane : 0;
    const char* base = (const char*)in;

    float4 b4 = *reinterpret_cast<const float4*>(bias + fo);
    float4 rA4 = make_float4(0.f,0.f,0.f,0.f), rB4 = rA4;
    int iA = 0, nA = 0, iB = 0, nB = 0;
    float diA = 0.f, diB = 0.f;
    if (dA < N) {
        iA = off4[dA]; nA = off4[dA + 1] - iA; diA = dinv[dA];
        rA4 = *reinterpret_cast<const float4*>(root + (long)dA * FDIM + fo);
    }
    if (dB < N) {
        iB = off4[dB]; nB = off4[dB + 1] - iB; diB = dinv[dB];
        rB4 = *reinterpret_cast<const float4*>(root + (long)dB * FDIM + fo);
    }

    GATHER_LOOP();

    if (ld) {
        if (dA < N) {
            float v0 = aA0 * diA + rA4.x + b4.x;
            float v1 = aA1 * diA + rA4.y + b4.y;
            float v2 = aA2 * diA + rA4.z + b4.z;
            float v3 = aA3 * diA + rA4.w + b4.w;
            if (RELU) { v0=fmaxf(v0,0.f); v1=fmaxf(v1,0.f); v2=fmaxf(v2,0.f); v3=fmaxf(v3,0.f); }
            sv[j][4*lane] = v0; sv[j][4*lane+1] = v1; sv[j][4*lane+2] = v2; sv[j][4*lane+3] = v3;
        }
        if (dB < N) {
            float v0 = aB0 * diB + rB4.x + b4.x;
            float v1 = aB1 * diB + rB4.y + b4.y;
            float v2 = aB2 * diB + rB4.z + b4.z;
            float v3 = aB3 * diB + rB4.w + b4.w;
            if (RELU) { v0=fmaxf(v0,0.f); v1=fmaxf(v1,0.f); v2=fmaxf(v2,0.f); v3=fmaxf(v3,0.f); }
            sv[j+8][4*lane] = v0; sv[j+8][4*lane+1] = v1; sv[j+8][4*lane+2] = v2; sv[j+8][4*lane+3] = v3;
        }
    }
    // same-wave LDS write->read: no barrier needed
    if (dA < N) {
        float o0 = 0.f, o1 = 0.f, o2 = 0.f;
        #pragma unroll
        for (int f = 0; f < 32; ++f) {
            o0 += sv[j][f]      * sw[f * 32 + lane];
            o1 += sv[j][32 + f] * sw[(32 + f) * 32 + lane];
            o2 += sv[j][64 + f] * sw[(64 + f) * 32 + lane];
        }
        out[(long)dA * FDIM + lane]      = __float2bfloat16(o0 * diA);
        out[(long)dA * FDIM + 32 + lane] = __float2bfloat16(o1 * diA);
        out[(long)dA * FDIM + 64 + lane] = __float2bfloat16(o2 * diA);
    }
    if (dB < N) {
        float o0 = 0.f, o1 = 0.f, o2 = 0.f;
        #pragma unroll
        for (int f = 0; f < 32; ++f) {
            o0 += sv[j+8][f]      * sw[f * 32 + lane];
            o1 += sv[j+8][32 + f] * sw[(32 + f) * 32 + lane];
            o2 += sv[j+8][64 + f] * sw[(64 + f) * 32 + lane];
        }
        out[(long)dB * FDIM + lane]      = __float2bfloat16(o0 * diB);
        out[(long)dB * FDIM + 32 + lane] = __float2bfloat16(o1 * diB);
        out[(long)dB * FDIM + 64 + lane] = __float2bfloat16(o2 * diB);
    }
}

// ---------------- prop #2: gather + act + mean over stacks -------------
template <bool RELU, bool OUTER_RELU>
__global__ __launch_bounds__(256) void prop_mean_kernel(
    const bf16*  __restrict__ in,       // [N+1, 96] pre-scaled by dinv[src]
    const int*   __restrict__ off4,
    const int*   __restrict__ csr,
    const float* __restrict__ dinv,
    const float* __restrict__ root,     // [N, 96]
    const float* __restrict__ bias,     // [96]
    float* __restrict__ out,            // [N, 32]
    int N)
{
    __shared__ float sv[16][FDIM];
    const int tid = threadIdx.x;
    const int lane = tid & 31;
    const int j    = tid >> 5;
    const int dA   = blockIdx.x * 16 + j;
    const int dB   = dA + 8;
    const int dummy = N * ROWB;
    const bool ld  = lane < 24;
    const int  lb  = lane * 8;
    const int  fo  = ld ? 4 * lane : 0;
    const char* base = (const char*)in;

    float4 b4 = *reinterpret_cast<const float4*>(bias + fo);
    float4 rA4 = make_float4(0.f,0.f,0.f,0.f), rB4 = rA4;
    int iA = 0, nA = 0, iB = 0, nB = 0;
    float diA = 0.f, diB = 0.f;
    if (dA < N) {
        iA = off4[dA]; nA = off4[dA + 1] - iA; diA = dinv[dA];
        rA4 = *reinterpret_cast<const float4*>(root + (long)dA * FDIM + fo);
    }
    if (dB < N) {
        iB = off4[dB]; nB = off4[dB + 1] - iB; diB = dinv[dB];
        rB4 = *reinterpret_cast<const float4*>(root + (long)dB * FDIM + fo);
    }

    GATHER_LOOP();

    if (ld) {
        if (dA < N) {
            float v0 = aA0 * diA + rA4.x + b4.x;
            float v1 = aA1 * diA + rA4.y + b4.y;
            float v2 = aA2 * diA + rA4.z + b4.z;
            float v3 = aA3 * diA + rA4.w + b4.w;
            if (RELU) { v0=fmaxf(v0,0.f); v1=fmaxf(v1,0.f); v2=fmaxf(v2,0.f); v3=fmaxf(v3,0.f); }
            sv[j][4*lane] = v0; sv[j][4*lane+1] = v1; sv[j][4*lane+2] = v2; sv[j][4*lane+3] = v3;
        }
        if (dB < N) {
            float v0 = aB0 * diB + rB4.x + b4.x;
            float v1 = aB1 * diB + rB4.y + b4.y;
            float v2 = aB2 * diB + rB4.z + b4.z;
            float v3 = aB3 * diB + rB4.w + b4.w;
            if (RELU) { v0=fmaxf(v0,0.f); v1=fmaxf(v1,0.f); v2=fmaxf(v2,0.f); v3=fmaxf(v3,0.f); }
            sv[j+8][4*lane] = v0; sv[j+8][4*lane+1] = v1; sv[j+8][4*lane+2] = v2; sv[j+8][4*lane+3] = v3;
        }
    }
    if (dA < N) {
        float mv = (sv[j][lane] + sv[j][32 + lane] + sv[j][64 + lane]) * (1.0f / 3.0f);
        if (OUTER_RELU) mv = fmaxf(mv, 0.f);
        out[(long)dA * 32 + lane] = mv;
    }
    if (dB < N) {
        float mv = (sv[j+8][lane] + sv[j+8][32 + lane] + sv[j+8][64 + lane]) * (1.0f / 3.0f);
        if (OUTER_RELU) mv = fmaxf(mv, 0.f);
        out[(long)dB * 32 + lane] = mv;
    }
}

// ---------------- launch ----------------

extern "C" void kernel_launch(void* const* d_in, const int* in_sizes, int n_in,
                              void* d_out, int out_size, void* d_ws, size_t ws_size,
                              hipStream_t stream) {
    const float* x       = (const float*)d_in[0];
    const int*   edge    = (const int*)  d_in[1];
    const float* w1_init = (const float*)d_in[2];
    const float* w1      = (const float*)d_in[3];
    const float* w1_root = (const float*)d_in[4];
    const float* b1      = (const float*)d_in[5];
    const float* w2_init = (const float*)d_in[6];
    const float* w2      = (const float*)d_in[7];
    const float* w2_root = (const float*)d_in[8];
    const float* b2      = (const float*)d_in[9];
    float* out = (float*)d_out;

    const int N = in_sizes[0] / 64;
    const int E = in_sizes[1] / 2;
    const int* src = edge;
    const int* dst = edge + E;
    const int E4max = E + 3 * N;   // upper bound on padded CSR length

    // workspace carve (256B aligned)
    char* p = (char*)d_ws;
    auto alloc = [&](size_t bytes) { void* r = (void*)p; p += (bytes + 255) & ~(size_t)255; return r; };
    int*   deg      = (int*)  alloc((size_t)N * 4);
    float* dinv     = (float*)alloc((size_t)N * 4);
    int*   off4     = (int*)  alloc((size_t)(N + 1) * 4);
    int*   cursor   = (int*)  alloc((size_t)N * 4);
    const int nScanBlocks = (N + 1 + 511) / 512;
    int*   bsums    = (int*)  alloc((size_t)nScanBlocks * 4);
    int*   bcnt     = (int*)  alloc((size_t)NB * 4);
    int*   gcur     = (int*)  alloc((size_t)NB * 4);
    int*   csr_boff = (int*)  alloc((size_t)(E4max + 1024) * 4);
    bf16*  gatherA  = (bf16*) alloc((size_t)(N + 1) * FDIM * 2);
    bf16*  gatherB  = (bf16*) alloc((size_t)(N + 1) * FDIM * 2);
    float* rootb    = (float*)alloc((size_t)N * FDIM * 4);
    float* hbuf     = (float*)alloc((size_t)N * DIM * 4);
    int2*  grouped  = (int2*)rootb;   // alias: grouped consumed before rootb written
    (void)ws_size; (void)n_in; (void)out_size;

    const int gN     = (N + 255) / 256;
    const int gN1    = (N + 1 + 255) / 256;
    const int gE     = (E + 255) / 256;
    const int gT     = (E + TILE - 1) / TILE;
    const int gNod   = (N + 7) / 8;       // 8 rows per 256-thread block (mm_init)
    const int gNod16 = (N + 15) / 16;     // 16 dst per 256-thread block (props)

    // ---- graph structure (rebuilt every call; deterministic topology) ----
    zero_int_kernel<<<gN, 256, 0, stream>>>(deg, N);
    count_deg_kernel<<<gE, 256, 0, stream>>>(dst, deg, E);
    dinv_kernel<<<gN, 256, 0, stream>>>(deg, dinv, N);
    scan1_kernel<<<nScanBlocks, 512, 0, stream>>>(deg, off4, bsums, N);
    scan2_kernel<<<1, 64, 0, stream>>>(bsums, nScanBlocks);
    scan3_kernel<<<gN1, 256, 0, stream>>>(off4, cursor, bsums, N);
    bucket_sum_kernel<<<NB, 256, 0, stream>>>(deg, bcnt, N);
    bucket_scan_kernel<<<1, NB, 0, stream>>>(bcnt, gcur);
    group_edges_kernel<<<gT, 256, 0, stream>>>(src, dst, gcur, grouped, E);
    fill_csr_kernel<<<gE, 256, 0, stream>>>(grouped, cursor, csr_boff, E);
    pad_csr_kernel<<<gN, 256, 0, stream>>>(off4, deg, csr_boff, N, N * ROWB);
    zero_dummy_kernel<<<1, 96, 0, stream>>>(gatherA, gatherB, N);

    // ---- layer 1 (act = relu) ----
    mm_init_kernel<64><<<gNod, 256, 0, stream>>>(x, w1_init, w1_root, dinv, gatherA, rootb, N);
    prop_mm_kernel<true><<<gNod16, 256, 0, stream>>>(gatherA, off4, csr_boff, dinv, rootb, b1, w1, gatherB, N);
    prop_mean_kernel<true, true><<<gNod16, 256, 0, stream>>>(gatherB, off4, csr_boff, dinv, rootb, b1, hbuf, N);

    // ---- layer 2 (act = identity) ----
    mm_init_kernel<32><<<gNod, 256, 0, stream>>>(hbuf, w2_init, w2_root, dinv, gatherA, rootb, N);
    prop_mm_kernel<false><<<gNod16, 256, 0, stream>>>(gatherA, off4, csr_boff, dinv, rootb, b2, w2, gatherB, N);
    prop_mean_kernel<false, false><<<gNod16, 256, 0, stream>>>(gatherB, off4, csr_boff, dinv, rootb, b2, out, N);
}

// Round 6
// 517.215 us; speedup vs baseline: 1.7263x; 1.1390x over previous
//
#include <hip/hip_runtime.h>
#include <hip/hip_bf16.h>

// ARMA GNN (K=3 stacks, T=2 layers, F_in=64, DIM=32) on MI355X.
// Round 6: mm_init rebuilt — 64 nodes/block, bf16-packed {A,B} weights in one
// u32 LDS word, x staged transposed for ds_read_b128; 48 FMAs per 5 LDS reads.

#define KSTACK 3
#define DIM    32
#define FDIM   96    // KSTACK*DIM
#define ROWB   192   // bytes per feature row (96 bf16)
#define NB     256   // dst buckets (dst>>9; N<=131072)
#define TILE   4096  // edges per grouping block

typedef __hip_bfloat16 bf16;

// ---------------- CSR build ----------------

__global__ void zero_int_kernel(int* __restrict__ p, int n) {
    int i = blockIdx.x * 256 + threadIdx.x;
    if (i < n) p[i] = 0;
}

__global__ void count_deg_kernel(const int* __restrict__ dst, int* __restrict__ deg, int E) {
    int i = blockIdx.x * 256 + threadIdx.x;
    if (i < E) atomicAdd(&deg[dst[i]], 1);
}

__global__ void dinv_kernel(const int* __restrict__ deg, float* __restrict__ dinv, int N) {
    int i = blockIdx.x * 256 + threadIdx.x;
    if (i < N) {
        int d = deg[i];
        dinv[i] = (d > 0) ? rsqrtf((float)d) : 0.0f;
    }
}

// scans deg4 = roundup4(deg) over N+1 items (item N contributes 0)
__global__ __launch_bounds__(512) void scan1_kernel(const int* __restrict__ deg,
                                                    int* __restrict__ off4,
                                                    int* __restrict__ bsums, int N) {
    __shared__ int tmp[512];
    int t = threadIdx.x;
    int i = blockIdx.x * 512 + t;
    int v = (i < N) ? ((deg[i] + 3) & ~3) : 0;
    tmp[t] = v;
    __syncthreads();
    for (int off = 1; off < 512; off <<= 1) {
        int add = (t >= off) ? tmp[t - off] : 0;
        __syncthreads();
        tmp[t] += add;
        __syncthreads();
    }
    if (i <= N) off4[i] = tmp[t] - v;            // block-local exclusive
    if (t == 511) bsums[blockIdx.x] = tmp[511];  // block total
}

__global__ void scan2_kernel(int* __restrict__ bsums, int nb) {
    if (blockIdx.x == 0 && threadIdx.x == 0) {
        int run = 0;
        for (int b = 0; b < nb; ++b) { int v = bsums[b]; bsums[b] = run; run += v; }
    }
}

__global__ void scan3_kernel(int* __restrict__ off4, int* __restrict__ cursor,
                             const int* __restrict__ bsums, int N) {
    int i = blockIdx.x * 256 + threadIdx.x;
    if (i <= N) {
        int v = off4[i] + bsums[i >> 9];
        off4[i] = v;
        if (i < N) cursor[i] = v;
    }
}

// per-bucket edge counts from deg (bucket = 512 consecutive nodes)
__global__ __launch_bounds__(256) void bucket_sum_kernel(const int* __restrict__ deg,
                                                         int* __restrict__ bcnt, int N) {
    __shared__ int s[256];
    const int b = blockIdx.x, t = threadIdx.x;
    int i0 = b * 512 + t;
    int v = 0;
    if (i0 < N) v += deg[i0];
    if (i0 + 256 < N) v += deg[i0 + 256];
    s[t] = v;
    __syncthreads();
    for (int off = 128; off > 0; off >>= 1) {
        if (t < off) s[t] += s[t + off];
        __syncthreads();
    }
    if (t == 0) bcnt[b] = s[0];
}

__global__ __launch_bounds__(256) void bucket_scan_kernel(const int* __restrict__ bcnt,
                                                          int* __restrict__ gcur) {
    __shared__ int s[NB];
    const int t = threadIdx.x;
    int v = bcnt[t];
    s[t] = v;
    __syncthreads();
    for (int off = 1; off < NB; off <<= 1) {
        int add = (t >= off) ? s[t - off] : 0;
        __syncthreads();
        s[t] += add;
        __syncthreads();
    }
    gcur[t] = s[t] - v;   // exclusive base; doubles as global cursor
}

// counting-sort pass: group edges by dst>>9 with coalesced output writes
__global__ __launch_bounds__(256) void group_edges_kernel(
    const int* __restrict__ src, const int* __restrict__ dst,
    int* __restrict__ gcur, int2* __restrict__ grouped, int E)
{
    __shared__ int cnt[NB], pref[NB], lbase[NB], lofs[NB], gres[NB];
    __shared__ int2 stage[TILE];
    const int tid = threadIdx.x;
    const int e0 = blockIdx.x * TILE;
    const int count = min(TILE, E - e0);
    cnt[tid] = 0;
    __syncthreads();
    #pragma unroll
    for (int u = 0; u < TILE / 256; ++u) {
        int idx = u * 256 + tid;
        if (idx < count) atomicAdd(&cnt[dst[e0 + idx] >> 9], 1);
    }
    __syncthreads();
    int v = cnt[tid];
    pref[tid] = v;
    __syncthreads();
    for (int off = 1; off < NB; off <<= 1) {
        int add = (tid >= off) ? pref[tid - off] : 0;
        __syncthreads();
        pref[tid] += add;
        __syncthreads();
    }
    int ex = pref[tid] - v;
    lbase[tid] = ex;
    lofs[tid]  = ex;
    gres[tid] = atomicAdd(&gcur[tid], v);   // reserve global chunk for this block
    __syncthreads();
    #pragma unroll
    for (int u = 0; u < TILE / 256; ++u) {
        int idx = u * 256 + tid;
        if (idx < count) {
            int e = e0 + idx;
            int d = dst[e];
            int lp = atomicAdd(&lofs[d >> 9], 1);
            stage[lp] = make_int2(src[e] * ROWB, d);
        }
    }
    __syncthreads();
    for (int i = tid; i < count; i += 256) {
        int2 pr = stage[i];
        int b = pr.y >> 9;
        grouped[gres[b] + (i - lbase[b])] = pr;   // coalesced runs per bucket
    }
}

// fill CSR from bucket-grouped edges: scatter now hits ~32KB L2-local windows
__global__ void fill_csr_kernel(const int2* __restrict__ grouped, int* __restrict__ cursor,
                                int* __restrict__ csr_boff, int E) {
    int e = blockIdx.x * 256 + threadIdx.x;
    if (e < E) {
        int2 pr = grouped[e];
        int pos = atomicAdd(&cursor[pr.y], 1);
        csr_boff[pos] = pr.x;
    }
}

// write dummy-row offsets into the 0-3 pad slots of each node's segment
__global__ void pad_csr_kernel(const int* __restrict__ off4, const int* __restrict__ deg,
                               int* __restrict__ csr_boff, int N, int dummy) {
    int i = blockIdx.x * 256 + threadIdx.x;
    if (i < N) {
        int p = off4[i] + deg[i];
        int e = off4[i + 1];
        for (; p < e; ++p) csr_boff[p] = dummy;
    }
}

__global__ void zero_dummy_kernel(bf16* __restrict__ a, bf16* __restrict__ b, int N) {
    int t = threadIdx.x;
    if (t < FDIM) {
        bf16 z = __float2bfloat16(0.f);
        a[(long)N * FDIM + t] = z;
        b[(long)N * FDIM + t] = z;
    }
}

// ---------------- init GEMM ----------------
// 64 nodes/block; thread (g,o): nodes 8g..8g+7, output col o, all 3 stacks.
// Weights staged as packed bf16 {A(lo),B(hi)} u32; x staged transposed [f][64+4].

__device__ __forceinline__ unsigned int f2bf_bits(float v) {
    unsigned int u = __float_as_uint(v);
    return (u + 0x7fffu + ((u >> 16) & 1u)) >> 16;   // RNE
}

template <int FIN>
__global__ __launch_bounds__(256) void mm_init_kernel(
    const float* __restrict__ x,    // [N, FIN]
    const float* __restrict__ wA,   // [K, FIN, 32]
    const float* __restrict__ wB,   // [K, FIN, 32]
    const float* __restrict__ dinv, // [N]
    bf16*  __restrict__ outA,       // [N+1, 96] (row N maintained elsewhere)
    float* __restrict__ outB,       // [N, 96]
    int N)
{
    constexpr int NW = KSTACK * FIN * 32;
    __shared__ unsigned int swAB[NW];   // packed bf16 pair
    __shared__ float sx[FIN * 68];      // transposed, pad 64->68 (16B-aligned rows)
    const int tid = threadIdx.x;
    const int n0  = blockIdx.x * 64;

    for (int i = tid; i < NW; i += 256)
        swAB[i] = f2bf_bits(wA[i]) | (f2bf_bits(wB[i]) << 16);
    for (int i = tid; i < 64 * FIN; i += 256) {
        int jj = i / FIN, f = i % FIN;   // FIN is pow2
        int n = n0 + jj; if (n >= N) n = N - 1;
        sx[f * 68 + jj] = x[(long)n * FIN + f];
    }
    __syncthreads();

    const int o = tid & 31;
    const int g = tid >> 5;
    float accA[8][KSTACK];
    float accB[8][KSTACK];
    #pragma unroll
    for (int jj = 0; jj < 8; ++jj)
        #pragma unroll
        for (int k = 0; k < KSTACK; ++k) { accA[jj][k] = 0.f; accB[jj][k] = 0.f; }

    #pragma unroll 2
    for (int f = 0; f < FIN; ++f) {
        float4 xlo = *reinterpret_cast<const float4*>(&sx[f * 68 + 8 * g]);
        float4 xhi = *reinterpret_cast<const float4*>(&sx[f * 68 + 8 * g + 4]);
        float xv[8] = {xlo.x, xlo.y, xlo.z, xlo.w, xhi.x, xhi.y, xhi.z, xhi.w};
        #pragma unroll
        for (int k = 0; k < KSTACK; ++k) {
            unsigned int q = swAB[(k * FIN + f) * 32 + o];
            float wa = __uint_as_float(q << 16);
            float wb = __uint_as_float(q & 0xffff0000u);
            #pragma unroll
            for (int jj = 0; jj < 8; ++jj) {
                accA[jj][k] += xv[jj] * wa;
                accB[jj][k] += xv[jj] * wb;
            }
        }
    }

    #pragma unroll
    for (int jj = 0; jj < 8; ++jj) {
        long n = n0 + 8 * g + jj;
        if (n < N) {
            const float di = dinv[n];
            #pragma unroll
            for (int k = 0; k < KSTACK; ++k) {
                outA[n * FDIM + k * 32 + o] = __float2bfloat16(accA[jj][k] * di);
                outB[n * FDIM + k * 32 + o] = accB[jj][k];
            }
        }
    }
}

// ---------------- gather helpers ----------------

__device__ __forceinline__ void bacc(unsigned int q, float& lo, float& hi) {
    lo += __uint_as_float(q << 16);
    hi += __uint_as_float(q & 0xffff0000u);
}

// dual-dst gather: 8 independent row loads in flight per 32-lane group.
// Out-of-range rows are predicated to the dummy zero row (offset `dummy`).
#define GATHER_LOOP()                                                          \
    const int m = max(nA, nB);                                                 \
    float aA0=0.f,aA1=0.f,aA2=0.f,aA3=0.f;                                     \
    float aB0=0.f,aB1=0.f,aB2=0.f,aB3=0.f;                                     \
    for (int b = 0; b < m; b += 4) {                                           \
        int4 tA = *reinterpret_cast<const int4*>(csr + iA + b);                \
        int4 tB = *reinterpret_cast<const int4*>(csr + iB + b);                \
        const int rA = nA - b, rB = nB - b;                                    \
        int oA0 = rA > 0 ? tA.x : dummy;                                       \
        int oA1 = rA > 1 ? tA.y : dummy;                                       \
        int oA2 = rA > 2 ? tA.z : dummy;                                       \
        int oA3 = rA > 3 ? tA.w : dummy;                                       \
        int oB0 = rB > 0 ? tB.x : dummy;                                       \
        int oB1 = rB > 1 ? tB.y : dummy;                                       \
        int oB2 = rB > 2 ? tB.z : dummy;                                       \
        int oB3 = rB > 3 ? tB.w : dummy;                                       \
        if (ld) {                                                              \
            uint2 qA0 = *reinterpret_cast<const uint2*>(base + oA0 + lb);      \
            uint2 qA1 = *reinterpret_cast<const uint2*>(base + oA1 + lb);      \
            uint2 qA2 = *reinterpret_cast<const uint2*>(base + oA2 + lb);      \
            uint2 qA3 = *reinterpret_cast<const uint2*>(base + oA3 + lb);      \
            uint2 qB0 = *reinterpret_cast<const uint2*>(base + oB0 + lb);      \
            uint2 qB1 = *reinterpret_cast<const uint2*>(base + oB1 + lb);      \
            uint2 qB2 = *reinterpret_cast<const uint2*>(base + oB2 + lb);      \
            uint2 qB3 = *reinterpret_cast<const uint2*>(base + oB3 + lb);      \
            bacc(qA0.x,aA0,aA1); bacc(qA0.y,aA2,aA3);                          \
            bacc(qA1.x,aA0,aA1); bacc(qA1.y,aA2,aA3);                          \
            bacc(qA2.x,aA0,aA1); bacc(qA2.y,aA2,aA3);                          \
            bacc(qA3.x,aA0,aA1); bacc(qA3.y,aA2,aA3);                          \
            bacc(qB0.x,aB0,aB1); bacc(qB0.y,aB2,aB3);                          \
            bacc(qB1.x,aB0,aB1); bacc(qB1.y,aB2,aB3);                          \
            bacc(qB2.x,aB0,aB1); bacc(qB2.y,aB2,aB3);                          \
            bacc(qB3.x,aB0,aB1); bacc(qB3.y,aB2,aB3);                          \
        }                                                                      \
    }

// ---------------- prop #1: gather + act + fused 32x32 GEMV ----------------
template <bool RELU>
__global__ __launch_bounds__(256) void prop_mm_kernel(
    const bf16*  __restrict__ in,       // [N+1, 96] pre-scaled by dinv[src]
    const int*   __restrict__ off4,     // [N+1]
    const int*   __restrict__ csr,      // byte row offsets, 4-aligned segments
    const float* __restrict__ dinv,
    const float* __restrict__ root,     // [N, 96]
    const float* __restrict__ bias,     // [96]
    const float* __restrict__ w,        // [K,32,32]
    bf16* __restrict__ out, int N)      // [N+1, 96]; row N maintained elsewhere
{
    __shared__ float sw[KSTACK * 32 * 32];
    __shared__ float sv[16][FDIM];
    const int tid = threadIdx.x;
    for (int i = tid; i < KSTACK * 32 * 32; i += 256) sw[i] = w[i];
    __syncthreads();
    const int lane = tid & 31;
    const int j    = tid >> 5;
    const int dA   = blockIdx.x * 16 + j;
    const int dB   = dA + 8;
    const int dummy = N * ROWB;
    const bool ld  = lane < 24;
    const int  lb  = lane * 8;
    const int  fo  = ld ? 4 * lane : 0;
    const char* base = (const char*)in;

    float4 b4 = *reinterpret_cast<const float4*>(bias + fo);
    float4 rA4 = make_float4(0.f,0.f,0.f,0.f), rB4 = rA4;
    int iA = 0, nA = 0, iB = 0, nB = 0;
    float diA = 0.f, diB = 0.f;
    if (dA < N) {
        iA = off4[dA]; nA = off4[dA + 1] - iA; diA = dinv[dA];
        rA4 = *reinterpret_cast<const float4*>(root + (long)dA * FDIM + fo);
    }
    if (dB < N) {
        iB = off4[dB]; nB = off4[dB + 1] - iB; diB = dinv[dB];
        rB4 = *reinterpret_cast<const float4*>(root + (long)dB * FDIM + fo);
    }

    GATHER_LOOP();

    if (ld) {
        if (dA < N) {
            float v0 = aA0 * diA + rA4.x + b4.x;
            float v1 = aA1 * diA + rA4.y + b4.y;
            float v2 = aA2 * diA + rA4.z + b4.z;
            float v3 = aA3 * diA + rA4.w + b4.w;
            if (RELU) { v0=fmaxf(v0,0.f); v1=fmaxf(v1,0.f); v2=fmaxf(v2,0.f); v3=fmaxf(v3,0.f); }
            sv[j][4*lane] = v0; sv[j][4*lane+1] = v1; sv[j][4*lane+2] = v2; sv[j][4*lane+3] = v3;
        }
        if (dB < N) {
            float v0 = aB0 * diB + rB4.x + b4.x;
            float v1 = aB1 * diB + rB4.y + b4.y;
            float v2 = aB2 * diB + rB4.z + b4.z;
            float v3 = aB3 * diB + rB4.w + b4.w;
            if (RELU) { v0=fmaxf(v0,0.f); v1=fmaxf(v1,0.f); v2=fmaxf(v2,0.f); v3=fmaxf(v3,0.f); }
            sv[j+8][4*lane] = v0; sv[j+8][4*lane+1] = v1; sv[j+8][4*lane+2] = v2; sv[j+8][4*lane+3] = v3;
        }
    }
    // same-wave LDS write->read: no barrier needed
    if (dA < N) {
        float o0 = 0.f, o1 = 0.f, o2 = 0.f;
        #pragma unroll
        for (int f = 0; f < 32; ++f) {
            o0 += sv[j][f]      * sw[f * 32 + lane];
            o1 += sv[j][32 + f] * sw[(32 + f) * 32 + lane];
            o2 += sv[j][64 + f] * sw[(64 + f) * 32 + lane];
        }
        out[(long)dA * FDIM + lane]      = __float2bfloat16(o0 * diA);
        out[(long)dA * FDIM + 32 + lane] = __float2bfloat16(o1 * diA);
        out[(long)dA * FDIM + 64 + lane] = __float2bfloat16(o2 * diA);
    }
    if (dB < N) {
        float o0 = 0.f, o1 = 0.f, o2 = 0.f;
        #pragma unroll
        for (int f = 0; f < 32; ++f) {
            o0 += sv[j+8][f]      * sw[f * 32 + lane];
            o1 += sv[j+8][32 + f] * sw[(32 + f) * 32 + lane];
            o2 += sv[j+8][64 + f] * sw[(64 + f) * 32 + lane];
        }
        out[(long)dB * FDIM + lane]      = __float2bfloat16(o0 * diB);
        out[(long)dB * FDIM + 32 + lane] = __float2bfloat16(o1 * diB);
        out[(long)dB * FDIM + 64 + lane] = __float2bfloat16(o2 * diB);
    }
}

// ---------------- prop #2: gather + act + mean over stacks -------------
template <bool RELU, bool OUTER_RELU>
__global__ __launch_bounds__(256) void prop_mean_kernel(
    const bf16*  __restrict__ in,       // [N+1, 96] pre-scaled by dinv[src]
    const int*   __restrict__ off4,
    const int*   __restrict__ csr,
    const float* __restrict__ dinv,
    const float* __restrict__ root,     // [N, 96]
    const float* __restrict__ bias,     // [96]
    float* __restrict__ out,            // [N, 32]
    int N)
{
    __shared__ float sv[16][FDIM];
    const int tid = threadIdx.x;
    const int lane = tid & 31;
    const int j    = tid >> 5;
    const int dA   = blockIdx.x * 16 + j;
    const int dB   = dA + 8;
    const int dummy = N * ROWB;
    const bool ld  = lane < 24;
    const int  lb  = lane * 8;
    const int  fo  = ld ? 4 * lane : 0;
    const char* base = (const char*)in;

    float4 b4 = *reinterpret_cast<const float4*>(bias + fo);
    float4 rA4 = make_float4(0.f,0.f,0.f,0.f), rB4 = rA4;
    int iA = 0, nA = 0, iB = 0, nB = 0;
    float diA = 0.f, diB = 0.f;
    if (dA < N) {
        iA = off4[dA]; nA = off4[dA + 1] - iA; diA = dinv[dA];
        rA4 = *reinterpret_cast<const float4*>(root + (long)dA * FDIM + fo);
    }
    if (dB < N) {
        iB = off4[dB]; nB = off4[dB + 1] - iB; diB = dinv[dB];
        rB4 = *reinterpret_cast<const float4*>(root + (long)dB * FDIM + fo);
    }

    GATHER_LOOP();

    if (ld) {
        if (dA < N) {
            float v0 = aA0 * diA + rA4.x + b4.x;
            float v1 = aA1 * diA + rA4.y + b4.y;
            float v2 = aA2 * diA + rA4.z + b4.z;
            float v3 = aA3 * diA + rA4.w + b4.w;
            if (RELU) { v0=fmaxf(v0,0.f); v1=fmaxf(v1,0.f); v2=fmaxf(v2,0.f); v3=fmaxf(v3,0.f); }
            sv[j][4*lane] = v0; sv[j][4*lane+1] = v1; sv[j][4*lane+2] = v2; sv[j][4*lane+3] = v3;
        }
        if (dB < N) {
            float v0 = aB0 * diB + rB4.x + b4.x;
            float v1 = aB1 * diB + rB4.y + b4.y;
            float v2 = aB2 * diB + rB4.z + b4.z;
            float v3 = aB3 * diB + rB4.w + b4.w;
            if (RELU) { v0=fmaxf(v0,0.f); v1=fmaxf(v1,0.f); v2=fmaxf(v2,0.f); v3=fmaxf(v3,0.f); }
            sv[j+8][4*lane] = v0; sv[j+8][4*lane+1] = v1; sv[j+8][4*lane+2] = v2; sv[j+8][4*lane+3] = v3;
        }
    }
    if (dA < N) {
        float mv = (sv[j][lane] + sv[j][32 + lane] + sv[j][64 + lane]) * (1.0f / 3.0f);
        if (OUTER_RELU) mv = fmaxf(mv, 0.f);
        out[(long)dA * 32 + lane] = mv;
    }
    if (dB < N) {
        float mv = (sv[j+8][lane] + sv[j+8][32 + lane] + sv[j+8][64 + lane]) * (1.0f / 3.0f);
        if (OUTER_RELU) mv = fmaxf(mv, 0.f);
        out[(long)dB * 32 + lane] = mv;
    }
}

// ---------------- launch ----------------

extern "C" void kernel_launch(void* const* d_in, const int* in_sizes, int n_in,
                              void* d_out, int out_size, void* d_ws, size_t ws_size,
                              hipStream_t stream) {
    const float* x       = (const float*)d_in[0];
    const int*   edge    = (const int*)  d_in[1];
    const float* w1_init = (const float*)d_in[2];
    const float* w1      = (const float*)d_in[3];
    const float* w1_root = (const float*)d_in[4];
    const float* b1      = (const float*)d_in[5];
    const float* w2_init = (const float*)d_in[6];
    const float* w2      = (const float*)d_in[7];
    const float* w2_root = (const float*)d_in[8];
    const float* b2      = (const float*)d_in[9];
    float* out = (float*)d_out;

    const int N = in_sizes[0] / 64;
    const int E = in_sizes[1] / 2;
    const int* src = edge;
    const int* dst = edge + E;
    const int E4max = E + 3 * N;   // upper bound on padded CSR length

    // workspace carve (256B aligned)
    char* p = (char*)d_ws;
    auto alloc = [&](size_t bytes) { void* r = (void*)p; p += (bytes + 255) & ~(size_t)255; return r; };
    int*   deg      = (int*)  alloc((size_t)N * 4);
    float* dinv     = (float*)alloc((size_t)N * 4);
    int*   off4     = (int*)  alloc((size_t)(N + 1) * 4);
    int*   cursor   = (int*)  alloc((size_t)N * 4);
    const int nScanBlocks = (N + 1 + 511) / 512;
    int*   bsums    = (int*)  alloc((size_t)nScanBlocks * 4);
    int*   bcnt     = (int*)  alloc((size_t)NB * 4);
    int*   gcur     = (int*)  alloc((size_t)NB * 4);
    int*   csr_boff = (int*)  alloc((size_t)(E4max + 1024) * 4);
    bf16*  gatherA  = (bf16*) alloc((size_t)(N + 1) * FDIM * 2);
    bf16*  gatherB  = (bf16*) alloc((size_t)(N + 1) * FDIM * 2);
    float* rootb    = (float*)alloc((size_t)N * FDIM * 4);
    float* hbuf     = (float*)alloc((size_t)N * DIM * 4);
    int2*  grouped  = (int2*)rootb;   // alias: grouped consumed before rootb written
    (void)ws_size; (void)n_in; (void)out_size;

    const int gN     = (N + 255) / 256;
    const int gN1    = (N + 1 + 255) / 256;
    const int gE     = (E + 255) / 256;
    const int gT     = (E + TILE - 1) / TILE;
    const int gNod64 = (N + 63) / 64;     // 64 rows per block (mm_init)
    const int gNod16 = (N + 15) / 16;     // 16 dst per block (props)

    // ---- graph structure (rebuilt every call; deterministic topology) ----
    zero_int_kernel<<<gN, 256, 0, stream>>>(deg, N);
    count_deg_kernel<<<gE, 256, 0, stream>>>(dst, deg, E);
    dinv_kernel<<<gN, 256, 0, stream>>>(deg, dinv, N);
    scan1_kernel<<<nScanBlocks, 512, 0, stream>>>(deg, off4, bsums, N);
    scan2_kernel<<<1, 64, 0, stream>>>(bsums, nScanBlocks);
    scan3_kernel<<<gN1, 256, 0, stream>>>(off4, cursor, bsums, N);
    bucket_sum_kernel<<<NB, 256, 0, stream>>>(deg, bcnt, N);
    bucket_scan_kernel<<<1, NB, 0, stream>>>(bcnt, gcur);
    group_edges_kernel<<<gT, 256, 0, stream>>>(src, dst, gcur, grouped, E);
    fill_csr_kernel<<<gE, 256, 0, stream>>>(grouped, cursor, csr_boff, E);
    pad_csr_kernel<<<gN, 256, 0, stream>>>(off4, deg, csr_boff, N, N * ROWB);
    zero_dummy_kernel<<<1, 96, 0, stream>>>(gatherA, gatherB, N);

    // ---- layer 1 (act = relu) ----
    mm_init_kernel<64><<<gNod64, 256, 0, stream>>>(x, w1_init, w1_root, dinv, gatherA, rootb, N);
    prop_mm_kernel<true><<<gNod16, 256, 0, stream>>>(gatherA, off4, csr_boff, dinv, rootb, b1, w1, gatherB, N);
    prop_mean_kernel<true, true><<<gNod16, 256, 0, stream>>>(gatherB, off4, csr_boff, dinv, rootb, b1, hbuf, N);

    // ---- layer 2 (act = identity) ----
    mm_init_kernel<32><<<gNod64, 256, 0, stream>>>(hbuf, w2_init, w2_root, dinv, gatherA, rootb, N);
    prop_mm_kernel<false><<<gNod16, 256, 0, stream>>>(gatherA, off4, csr_boff, dinv, rootb, b2, w2, gatherB, N);
    prop_mean_kernel<false, false><<<gNod16, 256, 0, stream>>>(gatherB, off4, csr_boff, dinv, rootb, b2, out, N);
}

// Round 7
// 481.378 us; speedup vs baseline: 1.8548x; 1.0744x over previous
//
#include <hip/hip_runtime.h>
#include <hip/hip_bf16.h>

// ARMA GNN (K=3 stacks, T=2 layers, F_in=64, DIM=32) on MI355X.
// Round 7: layer-2 exploits act=identity linearity -> k-mean propagated as
// 64B rows (L2-resident table); gather loops unrolled x8 (16 rows in flight).

#define KSTACK 3
#define DIM    32
#define FDIM   96    // KSTACK*DIM
#define NB     256   // dst buckets (dst>>9; N<=131072)
#define TILE   4096  // edges per grouping block

typedef __hip_bfloat16 bf16;

// ---------------- CSR build ----------------

__global__ void zero_int_kernel(int* __restrict__ p, int n) {
    int i = blockIdx.x * 256 + threadIdx.x;
    if (i < n) p[i] = 0;
}

__global__ void count_deg_kernel(const int* __restrict__ dst, int* __restrict__ deg, int E) {
    int i = blockIdx.x * 256 + threadIdx.x;
    if (i < E) atomicAdd(&deg[dst[i]], 1);
}

__global__ void dinv_kernel(const int* __restrict__ deg, float* __restrict__ dinv, int N) {
    int i = blockIdx.x * 256 + threadIdx.x;
    if (i < N) {
        int d = deg[i];
        dinv[i] = (d > 0) ? rsqrtf((float)d) : 0.0f;
    }
}

// scans deg4 = roundup4(deg) over N+1 items (item N contributes 0)
__global__ __launch_bounds__(512) void scan1_kernel(const int* __restrict__ deg,
                                                    int* __restrict__ off4,
                                                    int* __restrict__ bsums, int N) {
    __shared__ int tmp[512];
    int t = threadIdx.x;
    int i = blockIdx.x * 512 + t;
    int v = (i < N) ? ((deg[i] + 3) & ~3) : 0;
    tmp[t] = v;
    __syncthreads();
    for (int off = 1; off < 512; off <<= 1) {
        int add = (t >= off) ? tmp[t - off] : 0;
        __syncthreads();
        tmp[t] += add;
        __syncthreads();
    }
    if (i <= N) off4[i] = tmp[t] - v;            // block-local exclusive
    if (t == 511) bsums[blockIdx.x] = tmp[511];  // block total
}

__global__ void scan2_kernel(int* __restrict__ bsums, int nb) {
    if (blockIdx.x == 0 && threadIdx.x == 0) {
        int run = 0;
        for (int b = 0; b < nb; ++b) { int v = bsums[b]; bsums[b] = run; run += v; }
    }
}

__global__ void scan3_kernel(int* __restrict__ off4, int* __restrict__ cursor,
                             const int* __restrict__ bsums, int N) {
    int i = blockIdx.x * 256 + threadIdx.x;
    if (i <= N) {
        int v = off4[i] + bsums[i >> 9];
        off4[i] = v;
        if (i < N) cursor[i] = v;
    }
}

// per-bucket edge counts from deg (bucket = 512 consecutive nodes)
__global__ __launch_bounds__(256) void bucket_sum_kernel(const int* __restrict__ deg,
                                                         int* __restrict__ bcnt, int N) {
    __shared__ int s[256];
    const int b = blockIdx.x, t = threadIdx.x;
    int i0 = b * 512 + t;
    int v = 0;
    if (i0 < N) v += deg[i0];
    if (i0 + 256 < N) v += deg[i0 + 256];
    s[t] = v;
    __syncthreads();
    for (int off = 128; off > 0; off >>= 1) {
        if (t < off) s[t] += s[t + off];
        __syncthreads();
    }
    if (t == 0) bcnt[b] = s[0];
}

__global__ __launch_bounds__(256) void bucket_scan_kernel(const int* __restrict__ bcnt,
                                                          int* __restrict__ gcur) {
    __shared__ int s[NB];
    const int t = threadIdx.x;
    int v = bcnt[t];
    s[t] = v;
    __syncthreads();
    for (int off = 1; off < NB; off <<= 1) {
        int add = (t >= off) ? s[t - off] : 0;
        __syncthreads();
        s[t] += add;
        __syncthreads();
    }
    gcur[t] = s[t] - v;   // exclusive base; doubles as global cursor
}

// counting-sort pass: group edges by dst>>9 with coalesced output writes
__global__ __launch_bounds__(256) void group_edges_kernel(
    const int* __restrict__ src, const int* __restrict__ dst,
    int* __restrict__ gcur, int2* __restrict__ grouped, int E)
{
    __shared__ int cnt[NB], pref[NB], lbase[NB], lofs[NB], gres[NB];
    __shared__ int2 stage[TILE];
    const int tid = threadIdx.x;
    const int e0 = blockIdx.x * TILE;
    const int count = min(TILE, E - e0);
    cnt[tid] = 0;
    __syncthreads();
    #pragma unroll
    for (int u = 0; u < TILE / 256; ++u) {
        int idx = u * 256 + tid;
        if (idx < count) atomicAdd(&cnt[dst[e0 + idx] >> 9], 1);
    }
    __syncthreads();
    int v = cnt[tid];
    pref[tid] = v;
    __syncthreads();
    for (int off = 1; off < NB; off <<= 1) {
        int add = (tid >= off) ? pref[tid - off] : 0;
        __syncthreads();
        pref[tid] += add;
        __syncthreads();
    }
    int ex = pref[tid] - v;
    lbase[tid] = ex;
    lofs[tid]  = ex;
    gres[tid] = atomicAdd(&gcur[tid], v);   // reserve global chunk for this block
    __syncthreads();
    #pragma unroll
    for (int u = 0; u < TILE / 256; ++u) {
        int idx = u * 256 + tid;
        if (idx < count) {
            int e = e0 + idx;
            int d = dst[e];
            int lp = atomicAdd(&lofs[d >> 9], 1);
            stage[lp] = make_int2(src[e] << 6, d);   // src*64: native 64B-row offset
        }
    }
    __syncthreads();
    for (int i = tid; i < count; i += 256) {
        int2 pr = stage[i];
        int b = pr.y >> 9;
        grouped[gres[b] + (i - lbase[b])] = pr;   // coalesced runs per bucket
    }
}

// fill CSR from bucket-grouped edges: scatter now hits ~32KB L2-local windows
__global__ void fill_csr_kernel(const int2* __restrict__ grouped, int* __restrict__ cursor,
                                int* __restrict__ csr_boff, int E) {
    int e = blockIdx.x * 256 + threadIdx.x;
    if (e < E) {
        int2 pr = grouped[e];
        int pos = atomicAdd(&cursor[pr.y], 1);
        csr_boff[pos] = pr.x;
    }
}

// write dummy-row offsets into the 0-3 pad slots of each node's segment
__global__ void pad_csr_kernel(const int* __restrict__ off4, const int* __restrict__ deg,
                               int* __restrict__ csr_boff, int N, int dummy) {
    int i = blockIdx.x * 256 + threadIdx.x;
    if (i < N) {
        int p = off4[i] + deg[i];
        int e = off4[i + 1];
        for (; p < e; ++p) csr_boff[p] = dummy;
    }
}

__global__ void zero_dummy_kernel(bf16* __restrict__ a, bf16* __restrict__ b,
                                  bf16* __restrict__ c, int N) {
    int t = threadIdx.x;
    bf16 z = __float2bfloat16(0.f);
    if (t < FDIM) {
        a[(long)N * FDIM + t] = z;
        b[(long)N * FDIM + t] = z;
    }
    if (t < DIM) c[(long)N * DIM + t] = z;
}

// ---------------- init GEMM ----------------
// 64 nodes/block; thread (g,o): nodes 8g..8g+7, output col o, all 3 stacks.
// Weights staged as packed bf16 {A(lo),B(hi)} u32; x staged transposed [f][64+4].

__device__ __forceinline__ unsigned int f2bf_bits(float v) {
    unsigned int u = __float_as_uint(v);
    return (u + 0x7fffu + ((u >> 16) & 1u)) >> 16;   // RNE
}

template <int FIN, bool MEANROOT>
__global__ __launch_bounds__(256) void mm_init_kernel(
    const float* __restrict__ x,    // [N, FIN]
    const float* __restrict__ wA,   // [K, FIN, 32]
    const float* __restrict__ wB,   // [K, FIN, 32]
    const float* __restrict__ dinv, // [N]
    bf16*  __restrict__ outA,       // [N+1, 96] (row N maintained elsewhere)
    float* __restrict__ outB,       // [N, 96]
    float* __restrict__ rootm,      // [N, 32] = mean_k(outB) + mean_k(bias)  (if MEANROOT)
    const float* __restrict__ bias, // [96]                                   (if MEANROOT)
    int N)
{
    constexpr int NW = KSTACK * FIN * 32;
    __shared__ unsigned int swAB[NW];   // packed bf16 pair
    __shared__ float sx[FIN * 68];      // transposed, pad 64->68 (16B-aligned rows)
    const int tid = threadIdx.x;
    const int n0  = blockIdx.x * 64;

    for (int i = tid; i < NW; i += 256)
        swAB[i] = f2bf_bits(wA[i]) | (f2bf_bits(wB[i]) << 16);
    for (int i = tid; i < 64 * FIN; i += 256) {
        int jj = i / FIN, f = i % FIN;   // FIN is pow2
        int n = n0 + jj; if (n >= N) n = N - 1;
        sx[f * 68 + jj] = x[(long)n * FIN + f];
    }
    __syncthreads();

    const int o = tid & 31;
    const int g = tid >> 5;
    float mb = 0.f;
    if (MEANROOT) mb = (bias[o] + bias[32 + o] + bias[64 + o]) * (1.0f / 3.0f);
    float accA[8][KSTACK];
    float accB[8][KSTACK];
    #pragma unroll
    for (int jj = 0; jj < 8; ++jj)
        #pragma unroll
        for (int k = 0; k < KSTACK; ++k) { accA[jj][k] = 0.f; accB[jj][k] = 0.f; }

    #pragma unroll 2
    for (int f = 0; f < FIN; ++f) {
        float4 xlo = *reinterpret_cast<const float4*>(&sx[f * 68 + 8 * g]);
        float4 xhi = *reinterpret_cast<const float4*>(&sx[f * 68 + 8 * g + 4]);
        float xv[8] = {xlo.x, xlo.y, xlo.z, xlo.w, xhi.x, xhi.y, xhi.z, xhi.w};
        #pragma unroll
        for (int k = 0; k < KSTACK; ++k) {
            unsigned int q = swAB[(k * FIN + f) * 32 + o];
            float wa = __uint_as_float(q << 16);
            float wb = __uint_as_float(q & 0xffff0000u);
            #pragma unroll
            for (int jj = 0; jj < 8; ++jj) {
                accA[jj][k] += xv[jj] * wa;
                accB[jj][k] += xv[jj] * wb;
            }
        }
    }

    #pragma unroll
    for (int jj = 0; jj < 8; ++jj) {
        long n = n0 + 8 * g + jj;
        if (n < N) {
            const float di = dinv[n];
            #pragma unroll
            for (int k = 0; k < KSTACK; ++k) {
                outA[n * FDIM + k * 32 + o] = __float2bfloat16(accA[jj][k] * di);
                outB[n * FDIM + k * 32 + o] = accB[jj][k];
            }
            if (MEANROOT)
                rootm[n * 32 + o] = (accB[jj][0] + accB[jj][1] + accB[jj][2]) * (1.0f / 3.0f) + mb;
        }
    }
}

// ---------------- gather helpers ----------------

__device__ __forceinline__ void bacc(unsigned int q, float& lo, float& hi) {
    lo += __uint_as_float(q << 16);
    hi += __uint_as_float(q & 0xffff0000u);
}

// dual-dst gather over 192B rows, unroll 8 (16 row-loads + 4 offset-loads in
// flight per 32-lane group). csr stores src*64; 192B-row offset = 3*o.
// Out-of-range slots are predicated to the dummy zero row.
#define GATHER_LOOP8()                                                         \
    const int m = max(nA, nB);                                                 \
    float aA0=0.f,aA1=0.f,aA2=0.f,aA3=0.f;                                     \
    float aB0=0.f,aB1=0.f,aB2=0.f,aB3=0.f;                                     \
    for (int b = 0; b < m; b += 8) {                                           \
        int4 tA0 = *reinterpret_cast<const int4*>(csr + iA + b);               \
        int4 tA1 = *reinterpret_cast<const int4*>(csr + iA + b + 4);           \
        int4 tB0 = *reinterpret_cast<const int4*>(csr + iB + b);               \
        int4 tB1 = *reinterpret_cast<const int4*>(csr + iB + b + 4);           \
        const int rA = nA - b, rB = nB - b;                                    \
        int oA0 = rA > 0 ? tA0.x : dummy;                                      \
        int oA1 = rA > 1 ? tA0.y : dummy;                                      \
        int oA2 = rA > 2 ? tA0.z : dummy;                                      \
        int oA3 = rA > 3 ? tA0.w : dummy;                                      \
        int oA4 = rA > 4 ? tA1.x : dummy;                                      \
        int oA5 = rA > 5 ? tA1.y : dummy;                                      \
        int oA6 = rA > 6 ? tA1.z : dummy;                                      \
        int oA7 = rA > 7 ? tA1.w : dummy;                                      \
        int oB0 = rB > 0 ? tB0.x : dummy;                                      \
        int oB1 = rB > 1 ? tB0.y : dummy;                                      \
        int oB2 = rB > 2 ? tB0.z : dummy;                                      \
        int oB3 = rB > 3 ? tB0.w : dummy;                                      \
        int oB4 = rB > 4 ? tB1.x : dummy;                                      \
        int oB5 = rB > 5 ? tB1.y : dummy;                                      \
        int oB6 = rB > 6 ? tB1.z : dummy;                                      \
        int oB7 = rB > 7 ? tB1.w : dummy;                                      \
        if (ld) {                                                              \
            uint2 qA0 = *reinterpret_cast<const uint2*>(base + 3 * oA0 + lb);  \
            uint2 qA1 = *reinterpret_cast<const uint2*>(base + 3 * oA1 + lb);  \
            uint2 qA2 = *reinterpret_cast<const uint2*>(base + 3 * oA2 + lb);  \
            uint2 qA3 = *reinterpret_cast<const uint2*>(base + 3 * oA3 + lb);  \
            uint2 qA4 = *reinterpret_cast<const uint2*>(base + 3 * oA4 + lb);  \
            uint2 qA5 = *reinterpret_cast<const uint2*>(base + 3 * oA5 + lb);  \
            uint2 qA6 = *reinterpret_cast<const uint2*>(base + 3 * oA6 + lb);  \
            uint2 qA7 = *reinterpret_cast<const uint2*>(base + 3 * oA7 + lb);  \
            uint2 qB0 = *reinterpret_cast<const uint2*>(base + 3 * oB0 + lb);  \
            uint2 qB1 = *reinterpret_cast<const uint2*>(base + 3 * oB1 + lb);  \
            uint2 qB2 = *reinterpret_cast<const uint2*>(base + 3 * oB2 + lb);  \
            uint2 qB3 = *reinterpret_cast<const uint2*>(base + 3 * oB3 + lb);  \
            uint2 qB4 = *reinterpret_cast<const uint2*>(base + 3 * oB4 + lb);  \
            uint2 qB5 = *reinterpret_cast<const uint2*>(base + 3 * oB5 + lb);  \
            uint2 qB6 = *reinterpret_cast<const uint2*>(base + 3 * oB6 + lb);  \
            uint2 qB7 = *reinterpret_cast<const uint2*>(base + 3 * oB7 + lb);  \
            bacc(qA0.x,aA0,aA1); bacc(qA0.y,aA2,aA3);                          \
            bacc(qA1.x,aA0,aA1); bacc(qA1.y,aA2,aA3);                          \
            bacc(qA2.x,aA0,aA1); bacc(qA2.y,aA2,aA3);                          \
            bacc(qA3.x,aA0,aA1); bacc(qA3.y,aA2,aA3);                          \
            bacc(qA4.x,aA0,aA1); bacc(qA4.y,aA2,aA3);                          \
            bacc(qA5.x,aA0,aA1); bacc(qA5.y,aA2,aA3);                          \
            bacc(qA6.x,aA0,aA1); bacc(qA6.y,aA2,aA3);                          \
            bacc(qA7.x,aA0,aA1); bacc(qA7.y,aA2,aA3);                          \
            bacc(qB0.x,aB0,aB1); bacc(qB0.y,aB2,aB3);                          \
            bacc(qB1.x,aB0,aB1); bacc(qB1.y,aB2,aB3);                          \
            bacc(qB2.x,aB0,aB1); bacc(qB2.y,aB2,aB3);                          \
            bacc(qB3.x,aB0,aB1); bacc(qB3.y,aB2,aB3);                          \
            bacc(qB4.x,aB0,aB1); bacc(qB4.y,aB2,aB3);                          \
            bacc(qB5.x,aB0,aB1); bacc(qB5.y,aB2,aB3);                          \
            bacc(qB6.x,aB0,aB1); bacc(qB6.y,aB2,aB3);                          \
            bacc(qB7.x,aB0,aB1); bacc(qB7.y,aB2,aB3);                          \
        }                                                                      \
    }

// ---------------- prop #1 (layer 1): gather + relu + fused 32x32 GEMV ------
__global__ __launch_bounds__(256) void prop_mm_kernel(
    const bf16*  __restrict__ in,       // [N+1, 96] pre-scaled by dinv[src]
    const int*   __restrict__ off4,     // [N+1]
    const int*   __restrict__ csr,      // src*64, 4-aligned segments
    const float* __restrict__ dinv,
    const float* __restrict__ root,     // [N, 96]
    const float* __restrict__ bias,     // [96]
    const float* __restrict__ w,        // [K,32,32]
    bf16* __restrict__ out, int N)      // [N+1, 96]; row N maintained elsewhere
{
    __shared__ float sw[KSTACK * 32 * 32];
    __shared__ float sv[16][FDIM];
    const int tid = threadIdx.x;
    for (int i = tid; i < KSTACK * 32 * 32; i += 256) sw[i] = w[i];
    __syncthreads();
    const int lane = tid & 31;
    const int j    = tid >> 5;
    const int dA   = blockIdx.x * 16 + j;
    const int dB   = dA + 8;
    const int dummy = N * 64;
    const bool ld  = lane < 24;
    const int  lb  = lane * 8;
    const int  fo  = ld ? 4 * lane : 0;
    const char* base = (const char*)in;

    float4 b4 = *reinterpret_cast<const float4*>(bias + fo);
    float4 rA4 = make_float4(0.f,0.f,0.f,0.f), rB4 = rA4;
    int iA = 0, nA = 0, iB = 0, nB = 0;
    float diA = 0.f, diB = 0.f;
    if (dA < N) {
        iA = off4[dA]; nA = off4[dA + 1] - iA; diA = dinv[dA];
        rA4 = *reinterpret_cast<const float4*>(root + (long)dA * FDIM + fo);
    }
    if (dB < N) {
        iB = off4[dB]; nB = off4[dB + 1] - iB; diB = dinv[dB];
        rB4 = *reinterpret_cast<const float4*>(root + (long)dB * FDIM + fo);
    }

    GATHER_LOOP8();

    if (ld) {
        if (dA < N) {
            float v0 = fmaxf(aA0 * diA + rA4.x + b4.x, 0.f);
            float v1 = fmaxf(aA1 * diA + rA4.y + b4.y, 0.f);
            float v2 = fmaxf(aA2 * diA + rA4.z + b4.z, 0.f);
            float v3 = fmaxf(aA3 * diA + rA4.w + b4.w, 0.f);
            sv[j][4*lane] = v0; sv[j][4*lane+1] = v1; sv[j][4*lane+2] = v2; sv[j][4*lane+3] = v3;
        }
        if (dB < N) {
            float v0 = fmaxf(aB0 * diB + rB4.x + b4.x, 0.f);
            float v1 = fmaxf(aB1 * diB + rB4.y + b4.y, 0.f);
            float v2 = fmaxf(aB2 * diB + rB4.z + b4.z, 0.f);
            float v3 = fmaxf(aB3 * diB + rB4.w + b4.w, 0.f);
            sv[j+8][4*lane] = v0; sv[j+8][4*lane+1] = v1; sv[j+8][4*lane+2] = v2; sv[j+8][4*lane+3] = v3;
        }
    }
    // same-wave LDS write->read: no barrier needed
    if (dA < N) {
        float o0 = 0.f, o1 = 0.f, o2 = 0.f;
        #pragma unroll
        for (int f = 0; f < 32; ++f) {
            o0 += sv[j][f]      * sw[f * 32 + lane];
            o1 += sv[j][32 + f] * sw[(32 + f) * 32 + lane];
            o2 += sv[j][64 + f] * sw[(64 + f) * 32 + lane];
        }
        out[(long)dA * FDIM + lane]      = __float2bfloat16(o0 * diA);
        out[(long)dA * FDIM + 32 + lane] = __float2bfloat16(o1 * diA);
        out[(long)dA * FDIM + 64 + lane] = __float2bfloat16(o2 * diA);
    }
    if (dB < N) {
        float o0 = 0.f, o1 = 0.f, o2 = 0.f;
        #pragma unroll
        for (int f = 0; f < 32; ++f) {
            o0 += sv[j+8][f]      * sw[f * 32 + lane];
            o1 += sv[j+8][32 + f] * sw[(32 + f) * 32 + lane];
            o2 += sv[j+8][64 + f] * sw[(64 + f) * 32 + lane];
        }
        out[(long)dB * FDIM + lane]      = __float2bfloat16(o0 * diB);
        out[(long)dB * FDIM + 32 + lane] = __float2bfloat16(o1 * diB);
        out[(long)dB * FDIM + 64 + lane] = __float2bfloat16(o2 * diB);
    }
}

// -------- prop #2 (layer 1): gather + relu + mean over stacks + relu -------
__global__ __launch_bounds__(256) void prop_mean_kernel(
    const bf16*  __restrict__ in,       // [N+1, 96] pre-scaled by dinv[src]
    const int*   __restrict__ off4,
    const int*   __restrict__ csr,
    const float* __restrict__ dinv,
    const float* __restrict__ root,     // [N, 96]
    const float* __restrict__ bias,     // [96]
    float* __restrict__ out,            // [N, 32]
    int N)
{
    __shared__ float sv[16][FDIM];
    const int tid = threadIdx.x;
    const int lane = tid & 31;
    const int j    = tid >> 5;
    const int dA   = blockIdx.x * 16 + j;
    const int dB   = dA + 8;
    const int dummy = N * 64;
    const bool ld  = lane < 24;
    const int  lb  = lane * 8;
    const int  fo  = ld ? 4 * lane : 0;
    const char* base = (const char*)in;

    float4 b4 = *reinterpret_cast<const float4*>(bias + fo);
    float4 rA4 = make_float4(0.f,0.f,0.f,0.f), rB4 = rA4;
    int iA = 0, nA = 0, iB = 0, nB = 0;
    float diA = 0.f, diB = 0.f;
    if (dA < N) {
        iA = off4[dA]; nA = off4[dA + 1] - iA; diA = dinv[dA];
        rA4 = *reinterpret_cast<const float4*>(root + (long)dA * FDIM + fo);
    }
    if (dB < N) {
        iB = off4[dB]; nB = off4[dB + 1] - iB; diB = dinv[dB];
        rB4 = *reinterpret_cast<const float4*>(root + (long)dB * FDIM + fo);
    }

    GATHER_LOOP8();

    if (ld) {
        if (dA < N) {
            sv[j][4*lane]   = fmaxf(aA0 * diA + rA4.x + b4.x, 0.f);
            sv[j][4*lane+1] = fmaxf(aA1 * diA + rA4.y + b4.y, 0.f);
            sv[j][4*lane+2] = fmaxf(aA2 * diA + rA4.z + b4.z, 0.f);
            sv[j][4*lane+3] = fmaxf(aA3 * diA + rA4.w + b4.w, 0.f);
        }
        if (dB < N) {
            sv[j+8][4*lane]   = fmaxf(aB0 * diB + rB4.x + b4.x, 0.f);
            sv[j+8][4*lane+1] = fmaxf(aB1 * diB + rB4.y + b4.y, 0.f);
            sv[j+8][4*lane+2] = fmaxf(aB2 * diB + rB4.z + b4.z, 0.f);
            sv[j+8][4*lane+3] = fmaxf(aB3 * diB + rB4.w + b4.w, 0.f);
        }
    }
    if (dA < N) {
        float mv = fmaxf((sv[j][lane] + sv[j][32 + lane] + sv[j][64 + lane]) * (1.0f / 3.0f), 0.f);
        out[(long)dA * 32 + lane] = mv;
    }
    if (dB < N) {
        float mv = fmaxf((sv[j+8][lane] + sv[j+8][32 + lane] + sv[j+8][64 + lane]) * (1.0f / 3.0f), 0.f);
        out[(long)dB * 32 + lane] = mv;
    }
}

// ---- prop #3 (layer 2): gather + identity + GEMV, write k-MEAN (32-wide) ---
__global__ __launch_bounds__(256) void prop_mm_mean_kernel(
    const bf16*  __restrict__ in,       // [N+1, 96] pre-scaled by dinv[src]
    const int*   __restrict__ off4,
    const int*   __restrict__ csr,
    const float* __restrict__ dinv,
    const float* __restrict__ root,     // [N, 96]
    const float* __restrict__ bias,     // [96]
    const float* __restrict__ w,        // [K,32,32]
    bf16* __restrict__ out, int N)      // [N+1, 32]; row N maintained elsewhere
{
    __shared__ float sw[KSTACK * 32 * 32];
    __shared__ float sv[16][FDIM];
    const int tid = threadIdx.x;
    for (int i = tid; i < KSTACK * 32 * 32; i += 256) sw[i] = w[i];
    __syncthreads();
    const int lane = tid & 31;
    const int j    = tid >> 5;
    const int dA   = blockIdx.x * 16 + j;
    const int dB   = dA + 8;
    const int dummy = N * 64;
    const bool ld  = lane < 24;
    const int  lb  = lane * 8;
    const int  fo  = ld ? 4 * lane : 0;
    const char* base = (const char*)in;

    float4 b4 = *reinterpret_cast<const float4*>(bias + fo);
    float4 rA4 = make_float4(0.f,0.f,0.f,0.f), rB4 = rA4;
    int iA = 0, nA = 0, iB = 0, nB = 0;
    float diA = 0.f, diB = 0.f;
    if (dA < N) {
        iA = off4[dA]; nA = off4[dA + 1] - iA; diA = dinv[dA];
        rA4 = *reinterpret_cast<const float4*>(root + (long)dA * FDIM + fo);
    }
    if (dB < N) {
        iB = off4[dB]; nB = off4[dB + 1] - iB; diB = dinv[dB];
        rB4 = *reinterpret_cast<const float4*>(root + (long)dB * FDIM + fo);
    }

    GATHER_LOOP8();

    if (ld) {
        if (dA < N) {
            sv[j][4*lane]   = aA0 * diA + rA4.x + b4.x;
            sv[j][4*lane+1] = aA1 * diA + rA4.y + b4.y;
            sv[j][4*lane+2] = aA2 * diA + rA4.z + b4.z;
            sv[j][4*lane+3] = aA3 * diA + rA4.w + b4.w;
        }
        if (dB < N) {
            sv[j+8][4*lane]   = aB0 * diB + rB4.x + b4.x;
            sv[j+8][4*lane+1] = aB1 * diB + rB4.y + b4.y;
            sv[j+8][4*lane+2] = aB2 * diB + rB4.z + b4.z;
            sv[j+8][4*lane+3] = aB3 * diB + rB4.w + b4.w;
        }
    }
    // same-wave LDS write->read: no barrier needed
    if (dA < N) {
        float o0 = 0.f, o1 = 0.f, o2 = 0.f;
        #pragma unroll
        for (int f = 0; f < 32; ++f) {
            o0 += sv[j][f]      * sw[f * 32 + lane];
            o1 += sv[j][32 + f] * sw[(32 + f) * 32 + lane];
            o2 += sv[j][64 + f] * sw[(64 + f) * 32 + lane];
        }
        out[(long)dA * 32 + lane] = __float2bfloat16((o0 + o1 + o2) * (diA * (1.0f / 3.0f)));
    }
    if (dB < N) {
        float o0 = 0.f, o1 = 0.f, o2 = 0.f;
        #pragma unroll
        for (int f = 0; f < 32; ++f) {
            o0 += sv[j+8][f]      * sw[f * 32 + lane];
            o1 += sv[j+8][32 + f] * sw[(32 + f) * 32 + lane];
            o2 += sv[j+8][64 + f] * sw[(64 + f) * 32 + lane];
        }
        out[(long)dB * 32 + lane] = __float2bfloat16((o0 + o1 + o2) * (diB * (1.0f / 3.0f)));
    }
}

// ---- prop #4 (layer 2, final): 64B-row gather + rootm add (fp32 out) ------
__global__ __launch_bounds__(256) void prop_mean2_kernel(
    const bf16*  __restrict__ in,       // [N+1, 32] k-mean rows, dinv-prescaled
    const int*   __restrict__ off4,
    const int*   __restrict__ csr,      // src*64
    const float* __restrict__ dinv,
    const float* __restrict__ rootm,    // [N, 32] mean_k(root) + mean_k(bias)
    float* __restrict__ out,            // [N, 32]
    int N)
{
    const int lane = threadIdx.x & 15;
    const int g    = threadIdx.x >> 4;      // 16 groups/block
    const int d    = blockIdx.x * 16 + g;
    if (d >= N) return;
    const int dummy = N * 64;
    const int lb = lane * 4;                 // 4B (2 features) per lane
    const char* base = (const char*)in;
    const int i0 = off4[d];
    const int n  = off4[d + 1] - i0;
    float a0 = 0.f, a1 = 0.f;
    for (int b = 0; b < n; b += 8) {
        int4 t0 = *reinterpret_cast<const int4*>(csr + i0 + b);
        int4 t1 = *reinterpret_cast<const int4*>(csr + i0 + b + 4);
        const int r = n - b;
        int o0 = r > 0 ? t0.x : dummy;
        int o1 = r > 1 ? t0.y : dummy;
        int o2 = r > 2 ? t0.z : dummy;
        int o3 = r > 3 ? t0.w : dummy;
        int o4 = r > 4 ? t1.x : dummy;
        int o5 = r > 5 ? t1.y : dummy;
        int o6 = r > 6 ? t1.z : dummy;
        int o7 = r > 7 ? t1.w : dummy;
        unsigned int q0 = *reinterpret_cast<const unsigned int*>(base + o0 + lb);
        unsigned int q1 = *reinterpret_cast<const unsigned int*>(base + o1 + lb);
        unsigned int q2 = *reinterpret_cast<const unsigned int*>(base + o2 + lb);
        unsigned int q3 = *reinterpret_cast<const unsigned int*>(base + o3 + lb);
        unsigned int q4 = *reinterpret_cast<const unsigned int*>(base + o4 + lb);
        unsigned int q5 = *reinterpret_cast<const unsigned int*>(base + o5 + lb);
        unsigned int q6 = *reinterpret_cast<const unsigned int*>(base + o6 + lb);
        unsigned int q7 = *reinterpret_cast<const unsigned int*>(base + o7 + lb);
        bacc(q0, a0, a1); bacc(q1, a0, a1); bacc(q2, a0, a1); bacc(q3, a0, a1);
        bacc(q4, a0, a1); bacc(q5, a0, a1); bacc(q6, a0, a1); bacc(q7, a0, a1);
    }
    const float di = dinv[d];
    float2 rm = *reinterpret_cast<const float2*>(rootm + (long)d * 32 + 2 * lane);
    float2 res = make_float2(a0 * di + rm.x, a1 * di + rm.y);
    *reinterpret_cast<float2*>(out + (long)d * 32 + 2 * lane) = res;
}

// ---------------- launch ----------------

extern "C" void kernel_launch(void* const* d_in, const int* in_sizes, int n_in,
                              void* d_out, int out_size, void* d_ws, size_t ws_size,
                              hipStream_t stream) {
    const float* x       = (const float*)d_in[0];
    const int*   edge    = (const int*)  d_in[1];
    const float* w1_init = (const float*)d_in[2];
    const float* w1      = (const float*)d_in[3];
    const float* w1_root = (const float*)d_in[4];
    const float* b1      = (const float*)d_in[5];
    const float* w2_init = (const float*)d_in[6];
    const float* w2      = (const float*)d_in[7];
    const float* w2_root = (const float*)d_in[8];
    const float* b2      = (const float*)d_in[9];
    float* out = (float*)d_out;

    const int N = in_sizes[0] / 64;
    const int E = in_sizes[1] / 2;
    const int* src = edge;
    const int* dst = edge + E;
    const int E4max = E + 3 * N;   // upper bound on padded CSR length

    // workspace carve (256B aligned)
    char* p = (char*)d_ws;
    auto alloc = [&](size_t bytes) { void* r = (void*)p; p += (bytes + 255) & ~(size_t)255; return r; };
    int*   deg      = (int*)  alloc((size_t)N * 4);
    float* dinv     = (float*)alloc((size_t)N * 4);
    int*   off4     = (int*)  alloc((size_t)(N + 1) * 4);
    int*   cursor   = (int*)  alloc((size_t)N * 4);
    const int nScanBlocks = (N + 1 + 511) / 512;
    int*   bsums    = (int*)  alloc((size_t)nScanBlocks * 4);
    int*   bcnt     = (int*)  alloc((size_t)NB * 4);
    int*   gcur     = (int*)  alloc((size_t)NB * 4);
    int*   csr_boff = (int*)  alloc((size_t)(E4max + 1024) * 4);
    bf16*  gatherA  = (bf16*) alloc((size_t)(N + 1) * FDIM * 2);
    bf16*  gatherB  = (bf16*) alloc((size_t)(N + 1) * FDIM * 2);
    bf16*  grow2    = (bf16*) alloc((size_t)(N + 1) * DIM * 2);
    float* rootb    = (float*)alloc((size_t)N * FDIM * 4);
    float* rootm    = (float*)alloc((size_t)N * DIM * 4);
    float* hbuf     = (float*)alloc((size_t)N * DIM * 4);
    int2*  grouped  = (int2*)rootb;   // alias: grouped consumed before rootb written
    (void)ws_size; (void)n_in; (void)out_size;

    const int gN     = (N + 255) / 256;
    const int gN1    = (N + 1 + 255) / 256;
    const int gE     = (E + 255) / 256;
    const int gT     = (E + TILE - 1) / TILE;
    const int gNod64 = (N + 63) / 64;     // 64 rows per block (mm_init)
    const int gNod16 = (N + 15) / 16;     // 16 dst per block (props)

    // ---- graph structure (rebuilt every call; deterministic topology) ----
    zero_int_kernel<<<gN, 256, 0, stream>>>(deg, N);
    count_deg_kernel<<<gE, 256, 0, stream>>>(dst, deg, E);
    dinv_kernel<<<gN, 256, 0, stream>>>(deg, dinv, N);
    scan1_kernel<<<nScanBlocks, 512, 0, stream>>>(deg, off4, bsums, N);
    scan2_kernel<<<1, 64, 0, stream>>>(bsums, nScanBlocks);
    scan3_kernel<<<gN1, 256, 0, stream>>>(off4, cursor, bsums, N);
    bucket_sum_kernel<<<NB, 256, 0, stream>>>(deg, bcnt, N);
    bucket_scan_kernel<<<1, NB, 0, stream>>>(bcnt, gcur);
    group_edges_kernel<<<gT, 256, 0, stream>>>(src, dst, gcur, grouped, E);
    fill_csr_kernel<<<gE, 256, 0, stream>>>(grouped, cursor, csr_boff, E);
    pad_csr_kernel<<<gN, 256, 0, stream>>>(off4, deg, csr_boff, N, N * 64);
    zero_dummy_kernel<<<1, 96, 0, stream>>>(gatherA, gatherB, grow2, N);

    // ---- layer 1 (act = relu) ----
    mm_init_kernel<64, false><<<gNod64, 256, 0, stream>>>(x, w1_init, w1_root, dinv, gatherA, rootb, nullptr, nullptr, N);
    prop_mm_kernel<<<gNod16, 256, 0, stream>>>(gatherA, off4, csr_boff, dinv, rootb, b1, w1, gatherB, N);
    prop_mean_kernel<<<gNod16, 256, 0, stream>>>(gatherB, off4, csr_boff, dinv, rootb, b1, hbuf, N);

    // ---- layer 2 (act = identity; mean_k commutes through the tail) ----
    mm_init_kernel<32, true><<<gNod64, 256, 0, stream>>>(hbuf, w2_init, w2_root, dinv, gatherA, rootb, rootm, b2, N);
    prop_mm_mean_kernel<<<gNod16, 256, 0, stream>>>(gatherA, off4, csr_boff, dinv, rootb, b2, w2, grow2, N);
    prop_mean2_kernel<<<gNod16, 256, 0, stream>>>(grow2, off4, csr_boff, dinv, rootm, out, N);
}

// Round 8
// 460.356 us; speedup vs baseline: 1.9395x; 1.0457x over previous
//
#include <hip/hip_runtime.h>
#include <hip/hip_bf16.h>

// ARMA GNN (K=3 stacks, T=2 layers, F_in=64, DIM=32) on MI355X.
// Round 8: fused GEMV rebuilt around packed-f16 LDS + v_dot2_f32_f16
// (halves GEMV LDS traffic, 2x fewer MACs); gather accumulators use
// packed-f32 (v_pk_add_f32) via float2 ext-vectors.

#define KSTACK 3
#define DIM    32
#define FDIM   96    // KSTACK*DIM
#define NB     256   // dst buckets (dst>>9; N<=131072)
#define TILE   4096  // edges per grouping block

typedef __hip_bfloat16 bf16;
typedef _Float16 halfx2 __attribute__((ext_vector_type(2)));
typedef float    floatx2 __attribute__((ext_vector_type(2)));

__device__ __forceinline__ float dot2h(unsigned int a, unsigned int b, float c) {
#if __has_builtin(__builtin_amdgcn_fdot2)
    return __builtin_amdgcn_fdot2(__builtin_bit_cast(halfx2, a),
                                  __builtin_bit_cast(halfx2, b), c, false);
#else
    halfx2 ha = __builtin_bit_cast(halfx2, a);
    halfx2 hb = __builtin_bit_cast(halfx2, b);
    return c + (float)ha.x * (float)hb.x + (float)ha.y * (float)hb.y;
#endif
}

__device__ __forceinline__ unsigned int pkh(float lo, float hi) {
    return __builtin_bit_cast(unsigned int, __builtin_amdgcn_cvt_pkrtz(lo, hi));
}

// ---------------- CSR build ----------------

__global__ void zero_int_kernel(int* __restrict__ p, int n) {
    int i = blockIdx.x * 256 + threadIdx.x;
    if (i < n) p[i] = 0;
}

__global__ void count_deg_kernel(const int* __restrict__ dst, int* __restrict__ deg, int E) {
    int i = blockIdx.x * 256 + threadIdx.x;
    if (i < E) atomicAdd(&deg[dst[i]], 1);
}

__global__ void dinv_kernel(const int* __restrict__ deg, float* __restrict__ dinv, int N) {
    int i = blockIdx.x * 256 + threadIdx.x;
    if (i < N) {
        int d = deg[i];
        dinv[i] = (d > 0) ? rsqrtf((float)d) : 0.0f;
    }
}

// scans deg4 = roundup4(deg) over N+1 items (item N contributes 0)
__global__ __launch_bounds__(512) void scan1_kernel(const int* __restrict__ deg,
                                                    int* __restrict__ off4,
                                                    int* __restrict__ bsums, int N) {
    __shared__ int tmp[512];
    int t = threadIdx.x;
    int i = blockIdx.x * 512 + t;
    int v = (i < N) ? ((deg[i] + 3) & ~3) : 0;
    tmp[t] = v;
    __syncthreads();
    for (int off = 1; off < 512; off <<= 1) {
        int add = (t >= off) ? tmp[t - off] : 0;
        __syncthreads();
        tmp[t] += add;
        __syncthreads();
    }
    if (i <= N) off4[i] = tmp[t] - v;            // block-local exclusive
    if (t == 511) bsums[blockIdx.x] = tmp[511];  // block total
}

__global__ void scan2_kernel(int* __restrict__ bsums, int nb) {
    if (blockIdx.x == 0 && threadIdx.x == 0) {
        int run = 0;
        for (int b = 0; b < nb; ++b) { int v = bsums[b]; bsums[b] = run; run += v; }
    }
}

__global__ void scan3_kernel(int* __restrict__ off4, int* __restrict__ cursor,
                             const int* __restrict__ bsums, int N) {
    int i = blockIdx.x * 256 + threadIdx.x;
    if (i <= N) {
        int v = off4[i] + bsums[i >> 9];
        off4[i] = v;
        if (i < N) cursor[i] = v;
    }
}

// per-bucket edge counts from deg (bucket = 512 consecutive nodes)
__global__ __launch_bounds__(256) void bucket_sum_kernel(const int* __restrict__ deg,
                                                         int* __restrict__ bcnt, int N) {
    __shared__ int s[256];
    const int b = blockIdx.x, t = threadIdx.x;
    int i0 = b * 512 + t;
    int v = 0;
    if (i0 < N) v += deg[i0];
    if (i0 + 256 < N) v += deg[i0 + 256];
    s[t] = v;
    __syncthreads();
    for (int off = 128; off > 0; off >>= 1) {
        if (t < off) s[t] += s[t + off];
        __syncthreads();
    }
    if (t == 0) bcnt[b] = s[0];
}

__global__ __launch_bounds__(256) void bucket_scan_kernel(const int* __restrict__ bcnt,
                                                          int* __restrict__ gcur) {
    __shared__ int s[NB];
    const int t = threadIdx.x;
    int v = bcnt[t];
    s[t] = v;
    __syncthreads();
    for (int off = 1; off < NB; off <<= 1) {
        int add = (t >= off) ? s[t - off] : 0;
        __syncthreads();
        s[t] += add;
        __syncthreads();
    }
    gcur[t] = s[t] - v;   // exclusive base; doubles as global cursor
}

// counting-sort pass: group edges by dst>>9 with coalesced output writes
__global__ __launch_bounds__(256) void group_edges_kernel(
    const int* __restrict__ src, const int* __restrict__ dst,
    int* __restrict__ gcur, int2* __restrict__ grouped, int E)
{
    __shared__ int cnt[NB], pref[NB], lbase[NB], lofs[NB], gres[NB];
    __shared__ int2 stage[TILE];
    const int tid = threadIdx.x;
    const int e0 = blockIdx.x * TILE;
    const int count = min(TILE, E - e0);
    cnt[tid] = 0;
    __syncthreads();
    #pragma unroll
    for (int u = 0; u < TILE / 256; ++u) {
        int idx = u * 256 + tid;
        if (idx < count) atomicAdd(&cnt[dst[e0 + idx] >> 9], 1);
    }
    __syncthreads();
    int v = cnt[tid];
    pref[tid] = v;
    __syncthreads();
    for (int off = 1; off < NB; off <<= 1) {
        int add = (tid >= off) ? pref[tid - off] : 0;
        __syncthreads();
        pref[tid] += add;
        __syncthreads();
    }
    int ex = pref[tid] - v;
    lbase[tid] = ex;
    lofs[tid]  = ex;
    gres[tid] = atomicAdd(&gcur[tid], v);   // reserve global chunk for this block
    __syncthreads();
    #pragma unroll
    for (int u = 0; u < TILE / 256; ++u) {
        int idx = u * 256 + tid;
        if (idx < count) {
            int e = e0 + idx;
            int d = dst[e];
            int lp = atomicAdd(&lofs[d >> 9], 1);
            stage[lp] = make_int2(src[e] << 6, d);   // src*64: native 64B-row offset
        }
    }
    __syncthreads();
    for (int i = tid; i < count; i += 256) {
        int2 pr = stage[i];
        int b = pr.y >> 9;
        grouped[gres[b] + (i - lbase[b])] = pr;   // coalesced runs per bucket
    }
}

// fill CSR from bucket-grouped edges: scatter now hits ~32KB L2-local windows
__global__ void fill_csr_kernel(const int2* __restrict__ grouped, int* __restrict__ cursor,
                                int* __restrict__ csr_boff, int E) {
    int e = blockIdx.x * 256 + threadIdx.x;
    if (e < E) {
        int2 pr = grouped[e];
        int pos = atomicAdd(&cursor[pr.y], 1);
        csr_boff[pos] = pr.x;
    }
}

// write dummy-row offsets into the 0-3 pad slots of each node's segment
__global__ void pad_csr_kernel(const int* __restrict__ off4, const int* __restrict__ deg,
                               int* __restrict__ csr_boff, int N, int dummy) {
    int i = blockIdx.x * 256 + threadIdx.x;
    if (i < N) {
        int p = off4[i] + deg[i];
        int e = off4[i + 1];
        for (; p < e; ++p) csr_boff[p] = dummy;
    }
}

__global__ void zero_dummy_kernel(bf16* __restrict__ a, bf16* __restrict__ b,
                                  bf16* __restrict__ c, int N) {
    int t = threadIdx.x;
    bf16 z = __float2bfloat16(0.f);
    if (t < FDIM) {
        a[(long)N * FDIM + t] = z;
        b[(long)N * FDIM + t] = z;
    }
    if (t < DIM) c[(long)N * DIM + t] = z;
}

// ---------------- init GEMM ----------------
// 64 nodes/block; thread (g,o): nodes 8g..8g+7, output col o, all 3 stacks.
// Weights staged as packed bf16 {A(lo),B(hi)} u32; x staged transposed [f][64+4].

__device__ __forceinline__ unsigned int f2bf_bits(float v) {
    unsigned int u = __float_as_uint(v);
    return (u + 0x7fffu + ((u >> 16) & 1u)) >> 16;   // RNE
}

template <int FIN, bool MEANROOT>
__global__ __launch_bounds__(256) void mm_init_kernel(
    const float* __restrict__ x,    // [N, FIN]
    const float* __restrict__ wA,   // [K, FIN, 32]
    const float* __restrict__ wB,   // [K, FIN, 32]
    const float* __restrict__ dinv, // [N]
    bf16*  __restrict__ outA,       // [N+1, 96] (row N maintained elsewhere)
    float* __restrict__ outB,       // [N, 96]
    float* __restrict__ rootm,      // [N, 32] = mean_k(outB) + mean_k(bias)  (if MEANROOT)
    const float* __restrict__ bias, // [96]                                   (if MEANROOT)
    int N)
{
    constexpr int NW = KSTACK * FIN * 32;
    __shared__ unsigned int swAB[NW];   // packed bf16 pair
    __shared__ float sx[FIN * 68];      // transposed, pad 64->68 (16B-aligned rows)
    const int tid = threadIdx.x;
    const int n0  = blockIdx.x * 64;

    for (int i = tid; i < NW; i += 256)
        swAB[i] = f2bf_bits(wA[i]) | (f2bf_bits(wB[i]) << 16);
    for (int i = tid; i < 64 * FIN; i += 256) {
        int jj = i / FIN, f = i % FIN;   // FIN is pow2
        int n = n0 + jj; if (n >= N) n = N - 1;
        sx[f * 68 + jj] = x[(long)n * FIN + f];
    }
    __syncthreads();

    const int o = tid & 31;
    const int g = tid >> 5;
    float mb = 0.f;
    if (MEANROOT) mb = (bias[o] + bias[32 + o] + bias[64 + o]) * (1.0f / 3.0f);
    float accA[8][KSTACK];
    float accB[8][KSTACK];
    #pragma unroll
    for (int jj = 0; jj < 8; ++jj)
        #pragma unroll
        for (int k = 0; k < KSTACK; ++k) { accA[jj][k] = 0.f; accB[jj][k] = 0.f; }

    #pragma unroll 2
    for (int f = 0; f < FIN; ++f) {
        float4 xlo = *reinterpret_cast<const float4*>(&sx[f * 68 + 8 * g]);
        float4 xhi = *reinterpret_cast<const float4*>(&sx[f * 68 + 8 * g + 4]);
        float xv[8] = {xlo.x, xlo.y, xlo.z, xlo.w, xhi.x, xhi.y, xhi.z, xhi.w};
        #pragma unroll
        for (int k = 0; k < KSTACK; ++k) {
            unsigned int q = swAB[(k * FIN + f) * 32 + o];
            float wa = __uint_as_float(q << 16);
            float wb = __uint_as_float(q & 0xffff0000u);
            #pragma unroll
            for (int jj = 0; jj < 8; ++jj) {
                accA[jj][k] += xv[jj] * wa;
                accB[jj][k] += xv[jj] * wb;
            }
        }
    }

    #pragma unroll
    for (int jj = 0; jj < 8; ++jj) {
        long n = n0 + 8 * g + jj;
        if (n < N) {
            const float di = dinv[n];
            #pragma unroll
            for (int k = 0; k < KSTACK; ++k) {
                outA[n * FDIM + k * 32 + o] = __float2bfloat16(accA[jj][k] * di);
                outB[n * FDIM + k * 32 + o] = accB[jj][k];
            }
            if (MEANROOT)
                rootm[n * 32 + o] = (accB[jj][0] + accB[jj][1] + accB[jj][2]) * (1.0f / 3.0f) + mb;
        }
    }
}

// ---------------- gather helpers ----------------

__device__ __forceinline__ void bacc2(unsigned int q, floatx2& a) {
    floatx2 v;
    v.x = __uint_as_float(q << 16);
    v.y = __uint_as_float(q & 0xffff0000u);
    a += v;   // v_pk_add_f32
}

// dual-dst gather over 192B rows, unroll 8 (16 row-loads + 4 offset-loads in
// flight per 32-lane group). csr stores src*64; 192B-row offset = 3*o.
// Out-of-range slots are predicated to the dummy zero row.
#define GATHER_LOOP8()                                                         \
    const int m = max(nA, nB);                                                 \
    floatx2 aA01 = {0.f, 0.f}, aA23 = {0.f, 0.f};                              \
    floatx2 aB01 = {0.f, 0.f}, aB23 = {0.f, 0.f};                              \
    for (int b = 0; b < m; b += 8) {                                           \
        int4 tA0 = *reinterpret_cast<const int4*>(csr + iA + b);               \
        int4 tA1 = *reinterpret_cast<const int4*>(csr + iA + b + 4);           \
        int4 tB0 = *reinterpret_cast<const int4*>(csr + iB + b);               \
        int4 tB1 = *reinterpret_cast<const int4*>(csr + iB + b + 4);           \
        const int rA = nA - b, rB = nB - b;                                    \
        int oA0 = rA > 0 ? tA0.x : dummy;                                      \
        int oA1 = rA > 1 ? tA0.y : dummy;                                      \
        int oA2 = rA > 2 ? tA0.z : dummy;                                      \
        int oA3 = rA > 3 ? tA0.w : dummy;                                      \
        int oA4 = rA > 4 ? tA1.x : dummy;                                      \
        int oA5 = rA > 5 ? tA1.y : dummy;                                      \
        int oA6 = rA > 6 ? tA1.z : dummy;                                      \
        int oA7 = rA > 7 ? tA1.w : dummy;                                      \
        int oB0 = rB > 0 ? tB0.x : dummy;                                      \
        int oB1 = rB > 1 ? tB0.y : dummy;                                      \
        int oB2 = rB > 2 ? tB0.z : dummy;                                      \
        int oB3 = rB > 3 ? tB0.w : dummy;                                      \
        int oB4 = rB > 4 ? tB1.x : dummy;                                      \
        int oB5 = rB > 5 ? tB1.y : dummy;                                      \
        int oB6 = rB > 6 ? tB1.z : dummy;                                      \
        int oB7 = rB > 7 ? tB1.w : dummy;                                      \
        if (ld) {                                                              \
            uint2 qA0 = *reinterpret_cast<const uint2*>(base + 3 * oA0 + lb);  \
            uint2 qA1 = *reinterpret_cast<const uint2*>(base + 3 * oA1 + lb);  \
            uint2 qA2 = *reinterpret_cast<const uint2*>(base + 3 * oA2 + lb);  \
            uint2 qA3 = *reinterpret_cast<const uint2*>(base + 3 * oA3 + lb);  \
            uint2 qA4 = *reinterpret_cast<const uint2*>(base + 3 * oA4 + lb);  \
            uint2 qA5 = *reinterpret_cast<const uint2*>(base + 3 * oA5 + lb);  \
            uint2 qA6 = *reinterpret_cast<const uint2*>(base + 3 * oA6 + lb);  \
            uint2 qA7 = *reinterpret_cast<const uint2*>(base + 3 * oA7 + lb);  \
            uint2 qB0 = *reinterpret_cast<const uint2*>(base + 3 * oB0 + lb);  \
            uint2 qB1 = *reinterpret_cast<const uint2*>(base + 3 * oB1 + lb);  \
            uint2 qB2 = *reinterpret_cast<const uint2*>(base + 3 * oB2 + lb);  \
            uint2 qB3 = *reinterpret_cast<const uint2*>(base + 3 * oB3 + lb);  \
            uint2 qB4 = *reinterpret_cast<const uint2*>(base + 3 * oB4 + lb);  \
            uint2 qB5 = *reinterpret_cast<const uint2*>(base + 3 * oB5 + lb);  \
            uint2 qB6 = *reinterpret_cast<const uint2*>(base + 3 * oB6 + lb);  \
            uint2 qB7 = *reinterpret_cast<const uint2*>(base + 3 * oB7 + lb);  \
            bacc2(qA0.x, aA01); bacc2(qA0.y, aA23);                            \
            bacc2(qA1.x, aA01); bacc2(qA1.y, aA23);                            \
            bacc2(qA2.x, aA01); bacc2(qA2.y, aA23);                            \
            bacc2(qA3.x, aA01); bacc2(qA3.y, aA23);                            \
            bacc2(qA4.x, aA01); bacc2(qA4.y, aA23);                            \
            bacc2(qA5.x, aA01); bacc2(qA5.y, aA23);                            \
            bacc2(qA6.x, aA01); bacc2(qA6.y, aA23);                            \
            bacc2(qA7.x, aA01); bacc2(qA7.y, aA23);                            \
            bacc2(qB0.x, aB01); bacc2(qB0.y, aB23);                            \
            bacc2(qB1.x, aB01); bacc2(qB1.y, aB23);                            \
            bacc2(qB2.x, aB01); bacc2(qB2.y, aB23);                            \
            bacc2(qB3.x, aB01); bacc2(qB3.y, aB23);                            \
            bacc2(qB4.x, aB01); bacc2(qB4.y, aB23);                            \
            bacc2(qB5.x, aB01); bacc2(qB5.y, aB23);                            \
            bacc2(qB6.x, aB01); bacc2(qB6.y, aB23);                            \
            bacc2(qB7.x, aB01); bacc2(qB7.y, aB23);                            \
        }                                                                      \
    }

// packed-f16 96-wide GEMV: r_k = sum_f v[k*32+f] * w[k][f][lane]
__device__ __forceinline__ void gemv96(const unsigned int* __restrict__ sv,
                                       const unsigned int* __restrict__ sw2,
                                       int lane, float& r0, float& r1, float& r2) {
    float o[KSTACK];
    #pragma unroll
    for (int k = 0; k < KSTACK; ++k) {
        const unsigned int* sp = sv + k * 16;
        uint4 s0 = *reinterpret_cast<const uint4*>(sp);
        uint4 s1 = *reinterpret_cast<const uint4*>(sp + 4);
        uint4 s2 = *reinterpret_cast<const uint4*>(sp + 8);
        uint4 s3 = *reinterpret_cast<const uint4*>(sp + 12);
        const unsigned int* wp = sw2 + k * 512 + lane;
        float a = 0.f;
        a = dot2h(s0.x, wp[0],   a); a = dot2h(s0.y, wp[32],  a);
        a = dot2h(s0.z, wp[64],  a); a = dot2h(s0.w, wp[96],  a);
        a = dot2h(s1.x, wp[128], a); a = dot2h(s1.y, wp[160], a);
        a = dot2h(s1.z, wp[192], a); a = dot2h(s1.w, wp[224], a);
        a = dot2h(s2.x, wp[256], a); a = dot2h(s2.y, wp[288], a);
        a = dot2h(s2.z, wp[320], a); a = dot2h(s2.w, wp[352], a);
        a = dot2h(s3.x, wp[384], a); a = dot2h(s3.y, wp[416], a);
        a = dot2h(s3.z, wp[448], a); a = dot2h(s3.w, wp[480], a);
        o[k] = a;
    }
    r0 = o[0]; r1 = o[1]; r2 = o[2];
}

// ---------------- prop #1 (layer 1): gather + relu + fused 32x32 GEMV ------
__global__ __launch_bounds__(256) void prop_mm_kernel(
    const bf16*  __restrict__ in,       // [N+1, 96] pre-scaled by dinv[src]
    const int*   __restrict__ off4,     // [N+1]
    const int*   __restrict__ csr,      // src*64, 4-aligned segments
    const float* __restrict__ dinv,
    const float* __restrict__ root,     // [N, 96]
    const float* __restrict__ bias,     // [96]
    const float* __restrict__ w,        // [K,32,32]
    bf16* __restrict__ out, int N)      // [N+1, 96]; row N maintained elsewhere
{
    __shared__ unsigned int sw2[KSTACK * 512];   // lane-major packed-f16 weight pairs
    __shared__ unsigned int sv2[16][48];         // packed-f16 activated vectors
    const int tid = threadIdx.x;
    for (int i = tid; i < KSTACK * 512; i += 256) {
        int k = i >> 9, r = i & 511, t = r >> 5, o = r & 31;
        sw2[i] = pkh(w[(k * 32 + 2 * t) * 32 + o], w[(k * 32 + 2 * t + 1) * 32 + o]);
    }
    __syncthreads();
    const int lane = tid & 31;
    const int j    = tid >> 5;
    const int dA   = blockIdx.x * 16 + j;
    const int dB   = dA + 8;
    const int dummy = N * 64;
    const bool ld  = lane < 24;
    const int  lb  = lane * 8;
    const int  fo  = ld ? 4 * lane : 0;
    const char* base = (const char*)in;

    float4 b4 = *reinterpret_cast<const float4*>(bias + fo);
    float4 rA4 = make_float4(0.f,0.f,0.f,0.f), rB4 = rA4;
    int iA = 0, nA = 0, iB = 0, nB = 0;
    float diA = 0.f, diB = 0.f;
    if (dA < N) {
        iA = off4[dA]; nA = off4[dA + 1] - iA; diA = dinv[dA];
        rA4 = *reinterpret_cast<const float4*>(root + (long)dA * FDIM + fo);
    }
    if (dB < N) {
        iB = off4[dB]; nB = off4[dB + 1] - iB; diB = dinv[dB];
        rB4 = *reinterpret_cast<const float4*>(root + (long)dB * FDIM + fo);
    }

    GATHER_LOOP8();

    if (ld) {
        if (dA < N) {
            float v0 = fmaxf(aA01.x * diA + rA4.x + b4.x, 0.f);
            float v1 = fmaxf(aA01.y * diA + rA4.y + b4.y, 0.f);
            float v2 = fmaxf(aA23.x * diA + rA4.z + b4.z, 0.f);
            float v3 = fmaxf(aA23.y * diA + rA4.w + b4.w, 0.f);
            sv2[j][2 * lane]     = pkh(v0, v1);
            sv2[j][2 * lane + 1] = pkh(v2, v3);
        }
        if (dB < N) {
            float v0 = fmaxf(aB01.x * diB + rB4.x + b4.x, 0.f);
            float v1 = fmaxf(aB01.y * diB + rB4.y + b4.y, 0.f);
            float v2 = fmaxf(aB23.x * diB + rB4.z + b4.z, 0.f);
            float v3 = fmaxf(aB23.y * diB + rB4.w + b4.w, 0.f);
            sv2[j + 8][2 * lane]     = pkh(v0, v1);
            sv2[j + 8][2 * lane + 1] = pkh(v2, v3);
        }
    }
    // same-wave LDS write->read: no barrier needed
    if (dA < N) {
        float o0, o1, o2;
        gemv96(&sv2[j][0], sw2, lane, o0, o1, o2);
        out[(long)dA * FDIM + lane]      = __float2bfloat16(o0 * diA);
        out[(long)dA * FDIM + 32 + lane] = __float2bfloat16(o1 * diA);
        out[(long)dA * FDIM + 64 + lane] = __float2bfloat16(o2 * diA);
    }
    if (dB < N) {
        float o0, o1, o2;
        gemv96(&sv2[j + 8][0], sw2, lane, o0, o1, o2);
        out[(long)dB * FDIM + lane]      = __float2bfloat16(o0 * diB);
        out[(long)dB * FDIM + 32 + lane] = __float2bfloat16(o1 * diB);
        out[(long)dB * FDIM + 64 + lane] = __float2bfloat16(o2 * diB);
    }
}

// -------- prop #2 (layer 1): gather + relu + mean over stacks + relu -------
__global__ __launch_bounds__(256) void prop_mean_kernel(
    const bf16*  __restrict__ in,       // [N+1, 96] pre-scaled by dinv[src]
    const int*   __restrict__ off4,
    const int*   __restrict__ csr,
    const float* __restrict__ dinv,
    const float* __restrict__ root,     // [N, 96]
    const float* __restrict__ bias,     // [96]
    float* __restrict__ out,            // [N, 32]
    int N)
{
    __shared__ float sv[16][FDIM];
    const int tid = threadIdx.x;
    const int lane = tid & 31;
    const int j    = tid >> 5;
    const int dA   = blockIdx.x * 16 + j;
    const int dB   = dA + 8;
    const int dummy = N * 64;
    const bool ld  = lane < 24;
    const int  lb  = lane * 8;
    const int  fo  = ld ? 4 * lane : 0;
    const char* base = (const char*)in;

    float4 b4 = *reinterpret_cast<const float4*>(bias + fo);
    float4 rA4 = make_float4(0.f,0.f,0.f,0.f), rB4 = rA4;
    int iA = 0, nA = 0, iB = 0, nB = 0;
    float diA = 0.f, diB = 0.f;
    if (dA < N) {
        iA = off4[dA]; nA = off4[dA + 1] - iA; diA = dinv[dA];
        rA4 = *reinterpret_cast<const float4*>(root + (long)dA * FDIM + fo);
    }
    if (dB < N) {
        iB = off4[dB]; nB = off4[dB + 1] - iB; diB = dinv[dB];
        rB4 = *reinterpret_cast<const float4*>(root + (long)dB * FDIM + fo);
    }

    GATHER_LOOP8();

    if (ld) {
        if (dA < N) {
            sv[j][4*lane]   = fmaxf(aA01.x * diA + rA4.x + b4.x, 0.f);
            sv[j][4*lane+1] = fmaxf(aA01.y * diA + rA4.y + b4.y, 0.f);
            sv[j][4*lane+2] = fmaxf(aA23.x * diA + rA4.z + b4.z, 0.f);
            sv[j][4*lane+3] = fmaxf(aA23.y * diA + rA4.w + b4.w, 0.f);
        }
        if (dB < N) {
            sv[j+8][4*lane]   = fmaxf(aB01.x * diB + rB4.x + b4.x, 0.f);
            sv[j+8][4*lane+1] = fmaxf(aB01.y * diB + rB4.y + b4.y, 0.f);
            sv[j+8][4*lane+2] = fmaxf(aB23.x * diB + rB4.z + b4.z, 0.f);
            sv[j+8][4*lane+3] = fmaxf(aB23.y * diB + rB4.w + b4.w, 0.f);
        }
    }
    if (dA < N) {
        float mv = fmaxf((sv[j][lane] + sv[j][32 + lane] + sv[j][64 + lane]) * (1.0f / 3.0f), 0.f);
        out[(long)dA * 32 + lane] = mv;
    }
    if (dB < N) {
        float mv = fmaxf((sv[j+8][lane] + sv[j+8][32 + lane] + sv[j+8][64 + lane]) * (1.0f / 3.0f), 0.f);
        out[(long)dB * 32 + lane] = mv;
    }
}

// ---- prop #3 (layer 2): gather + identity + GEMV, write k-MEAN (32-wide) ---
__global__ __launch_bounds__(256) void prop_mm_mean_kernel(
    const bf16*  __restrict__ in,       // [N+1, 96] pre-scaled by dinv[src]
    const int*   __restrict__ off4,
    const int*   __restrict__ csr,
    const float* __restrict__ dinv,
    const float* __restrict__ root,     // [N, 96]
    const float* __restrict__ bias,     // [96]
    const float* __restrict__ w,        // [K,32,32]
    bf16* __restrict__ out, int N)      // [N+1, 32]; row N maintained elsewhere
{
    __shared__ unsigned int sw2[KSTACK * 512];
    __shared__ unsigned int sv2[16][48];
    const int tid = threadIdx.x;
    for (int i = tid; i < KSTACK * 512; i += 256) {
        int k = i >> 9, r = i & 511, t = r >> 5, o = r & 31;
        sw2[i] = pkh(w[(k * 32 + 2 * t) * 32 + o], w[(k * 32 + 2 * t + 1) * 32 + o]);
    }
    __syncthreads();
    const int lane = tid & 31;
    const int j    = tid >> 5;
    const int dA   = blockIdx.x * 16 + j;
    const int dB   = dA + 8;
    const int dummy = N * 64;
    const bool ld  = lane < 24;
    const int  lb  = lane * 8;
    const int  fo  = ld ? 4 * lane : 0;
    const char* base = (const char*)in;

    float4 b4 = *reinterpret_cast<const float4*>(bias + fo);
    float4 rA4 = make_float4(0.f,0.f,0.f,0.f), rB4 = rA4;
    int iA = 0, nA = 0, iB = 0, nB = 0;
    float diA = 0.f, diB = 0.f;
    if (dA < N) {
        iA = off4[dA]; nA = off4[dA + 1] - iA; diA = dinv[dA];
        rA4 = *reinterpret_cast<const float4*>(root + (long)dA * FDIM + fo);
    }
    if (dB < N) {
        iB = off4[dB]; nB = off4[dB + 1] - iB; diB = dinv[dB];
        rB4 = *reinterpret_cast<const float4*>(root + (long)dB * FDIM + fo);
    }

    GATHER_LOOP8();

    if (ld) {
        if (dA < N) {
            sv2[j][2 * lane]     = pkh(aA01.x * diA + rA4.x + b4.x, aA01.y * diA + rA4.y + b4.y);
            sv2[j][2 * lane + 1] = pkh(aA23.x * diA + rA4.z + b4.z, aA23.y * diA + rA4.w + b4.w);
        }
        if (dB < N) {
            sv2[j + 8][2 * lane]     = pkh(aB01.x * diB + rB4.x + b4.x, aB01.y * diB + rB4.y + b4.y);
            sv2[j + 8][2 * lane + 1] = pkh(aB23.x * diB + rB4.z + b4.z, aB23.y * diB + rB4.w + b4.w);
        }
    }
    // same-wave LDS write->read: no barrier needed
    if (dA < N) {
        float o0, o1, o2;
        gemv96(&sv2[j][0], sw2, lane, o0, o1, o2);
        out[(long)dA * 32 + lane] = __float2bfloat16((o0 + o1 + o2) * (diA * (1.0f / 3.0f)));
    }
    if (dB < N) {
        float o0, o1, o2;
        gemv96(&sv2[j + 8][0], sw2, lane, o0, o1, o2);
        out[(long)dB * 32 + lane] = __float2bfloat16((o0 + o1 + o2) * (diB * (1.0f / 3.0f)));
    }
}

// ---- prop #4 (layer 2, final): 64B-row gather + rootm add (fp32 out) ------
__global__ __launch_bounds__(256) void prop_mean2_kernel(
    const bf16*  __restrict__ in,       // [N+1, 32] k-mean rows, dinv-prescaled
    const int*   __restrict__ off4,
    const int*   __restrict__ csr,      // src*64
    const float* __restrict__ dinv,
    const float* __restrict__ rootm,    // [N, 32] mean_k(root) + mean_k(bias)
    float* __restrict__ out,            // [N, 32]
    int N)
{
    const int lane = threadIdx.x & 15;
    const int g    = threadIdx.x >> 4;      // 16 groups/block
    const int d    = blockIdx.x * 16 + g;
    if (d >= N) return;
    const int dummy = N * 64;
    const int lb = lane * 4;                 // 4B (2 features) per lane
    const char* base = (const char*)in;
    const int i0 = off4[d];
    const int n  = off4[d + 1] - i0;
    floatx2 a = {0.f, 0.f};
    for (int b = 0; b < n; b += 8) {
        int4 t0 = *reinterpret_cast<const int4*>(csr + i0 + b);
        int4 t1 = *reinterpret_cast<const int4*>(csr + i0 + b + 4);
        const int r = n - b;
        int o0 = r > 0 ? t0.x : dummy;
        int o1 = r > 1 ? t0.y : dummy;
        int o2 = r > 2 ? t0.z : dummy;
        int o3 = r > 3 ? t0.w : dummy;
        int o4 = r > 4 ? t1.x : dummy;
        int o5 = r > 5 ? t1.y : dummy;
        int o6 = r > 6 ? t1.z : dummy;
        int o7 = r > 7 ? t1.w : dummy;
        unsigned int q0 = *reinterpret_cast<const unsigned int*>(base + o0 + lb);
        unsigned int q1 = *reinterpret_cast<const unsigned int*>(base + o1 + lb);
        unsigned int q2 = *reinterpret_cast<const unsigned int*>(base + o2 + lb);
        unsigned int q3 = *reinterpret_cast<const unsigned int*>(base + o3 + lb);
        unsigned int q4 = *reinterpret_cast<const unsigned int*>(base + o4 + lb);
        unsigned int q5 = *reinterpret_cast<const unsigned int*>(base + o5 + lb);
        unsigned int q6 = *reinterpret_cast<const unsigned int*>(base + o6 + lb);
        unsigned int q7 = *reinterpret_cast<const unsigned int*>(base + o7 + lb);
        bacc2(q0, a); bacc2(q1, a); bacc2(q2, a); bacc2(q3, a);
        bacc2(q4, a); bacc2(q5, a); bacc2(q6, a); bacc2(q7, a);
    }
    const float di = dinv[d];
    float2 rm = *reinterpret_cast<const float2*>(rootm + (long)d * 32 + 2 * lane);
    float2 res = make_float2(a.x * di + rm.x, a.y * di + rm.y);
    *reinterpret_cast<float2*>(out + (long)d * 32 + 2 * lane) = res;
}

// ---------------- launch ----------------

extern "C" void kernel_launch(void* const* d_in, const int* in_sizes, int n_in,
                              void* d_out, int out_size, void* d_ws, size_t ws_size,
                              hipStream_t stream) {
    const float* x       = (const float*)d_in[0];
    const int*   edge    = (const int*)  d_in[1];
    const float* w1_init = (const float*)d_in[2];
    const float* w1      = (const float*)d_in[3];
    const float* w1_root = (const float*)d_in[4];
    const float* b1      = (const float*)d_in[5];
    const float* w2_init = (const float*)d_in[6];
    const float* w2      = (const float*)d_in[7];
    const float* w2_root = (const float*)d_in[8];
    const float* b2      = (const float*)d_in[9];
    float* out = (float*)d_out;

    const int N = in_sizes[0] / 64;
    const int E = in_sizes[1] / 2;
    const int* src = edge;
    const int* dst = edge + E;
    const int E4max = E + 3 * N;   // upper bound on padded CSR length

    // workspace carve (256B aligned)
    char* p = (char*)d_ws;
    auto alloc = [&](size_t bytes) { void* r = (void*)p; p += (bytes + 255) & ~(size_t)255; return r; };
    int*   deg      = (int*)  alloc((size_t)N * 4);
    float* dinv     = (float*)alloc((size_t)N * 4);
    int*   off4     = (int*)  alloc((size_t)(N + 1) * 4);
    int*   cursor   = (int*)  alloc((size_t)N * 4);
    const int nScanBlocks = (N + 1 + 511) / 512;
    int*   bsums    = (int*)  alloc((size_t)nScanBlocks * 4);
    int*   bcnt     = (int*)  alloc((size_t)NB * 4);
    int*   gcur     = (int*)  alloc((size_t)NB * 4);
    int*   csr_boff = (int*)  alloc((size_t)(E4max + 1024) * 4);
    bf16*  gatherA  = (bf16*) alloc((size_t)(N + 1) * FDIM * 2);
    bf16*  gatherB  = (bf16*) alloc((size_t)(N + 1) * FDIM * 2);
    bf16*  grow2    = (bf16*) alloc((size_t)(N + 1) * DIM * 2);
    float* rootb    = (float*)alloc((size_t)N * FDIM * 4);
    float* rootm    = (float*)alloc((size_t)N * DIM * 4);
    float* hbuf     = (float*)alloc((size_t)N * DIM * 4);
    int2*  grouped  = (int2*)rootb;   // alias: grouped consumed before rootb written
    (void)ws_size; (void)n_in; (void)out_size;

    const int gN     = (N + 255) / 256;
    const int gN1    = (N + 1 + 255) / 256;
    const int gE     = (E + 255) / 256;
    const int gT     = (E + TILE - 1) / TILE;
    const int gNod64 = (N + 63) / 64;     // 64 rows per block (mm_init)
    const int gNod16 = (N + 15) / 16;     // 16 dst per block (props)

    // ---- graph structure (rebuilt every call; deterministic topology) ----
    zero_int_kernel<<<gN, 256, 0, stream>>>(deg, N);
    count_deg_kernel<<<gE, 256, 0, stream>>>(dst, deg, E);
    dinv_kernel<<<gN, 256, 0, stream>>>(deg, dinv, N);
    scan1_kernel<<<nScanBlocks, 512, 0, stream>>>(deg, off4, bsums, N);
    scan2_kernel<<<1, 64, 0, stream>>>(bsums, nScanBlocks);
    scan3_kernel<<<gN1, 256, 0, stream>>>(off4, cursor, bsums, N);
    bucket_sum_kernel<<<NB, 256, 0, stream>>>(deg, bcnt, N);
    bucket_scan_kernel<<<1, NB, 0, stream>>>(bcnt, gcur);
    group_edges_kernel<<<gT, 256, 0, stream>>>(src, dst, gcur, grouped, E);
    fill_csr_kernel<<<gE, 256, 0, stream>>>(grouped, cursor, csr_boff, E);
    pad_csr_kernel<<<gN, 256, 0, stream>>>(off4, deg, csr_boff, N, N * 64);
    zero_dummy_kernel<<<1, 96, 0, stream>>>(gatherA, gatherB, grow2, N);

    // ---- layer 1 (act = relu) ----
    mm_init_kernel<64, false><<<gNod64, 256, 0, stream>>>(x, w1_init, w1_root, dinv, gatherA, rootb, nullptr, nullptr, N);
    prop_mm_kernel<<<gNod16, 256, 0, stream>>>(gatherA, off4, csr_boff, dinv, rootb, b1, w1, gatherB, N);
    prop_mean_kernel<<<gNod16, 256, 0, stream>>>(gatherB, off4, csr_boff, dinv, rootb, b1, hbuf, N);

    // ---- layer 2 (act = identity; mean_k commutes through the tail) ----
    mm_init_kernel<32, true><<<gNod64, 256, 0, stream>>>(hbuf, w2_init, w2_root, dinv, gatherA, rootb, rootm, b2, N);
    prop_mm_mean_kernel<<<gNod16, 256, 0, stream>>>(gatherA, off4, csr_boff, dinv, rootb, b2, w2, grow2, N);
    prop_mean2_kernel<<<gNod16, 256, 0, stream>>>(grow2, off4, csr_boff, dinv, rootm, out, N);
}